// Round 8
// baseline (1177.653 us; speedup 1.0000x reference)
//
#include <hip/hip_runtime.h>
#include <hip/hip_bf16.h>
#include <stdint.h>

#define NN 50000
#define EE 800000
#define GG 64
#define NOTESD 128
#define MPAD 50048
#define TM_TILES 391
#define NCHUNK 98
#define LDSW 40

typedef unsigned short u16;
typedef __attribute__((ext_vector_type(8))) short short8;
typedef __attribute__((ext_vector_type(4))) float f32x4;

__device__ __forceinline__ float b2f(u16 u) {
  union { uint32_t i; float f; } x; x.i = ((uint32_t)u) << 16; return x.f;
}
__device__ __forceinline__ u16 f2b(float f) {
  __hip_bfloat16 h = __float2bfloat16(f);
  return *reinterpret_cast<u16*>(&h);
}

// ---------------- CSR build ----------------
__global__ void k_hist(const int* __restrict__ dst, int* __restrict__ cnt) {
  int e = blockIdx.x * 256 + threadIdx.x;
  if (e < EE) atomicAdd(&cnt[dst[e]], 1);
}

__global__ void k_scan1(const int* __restrict__ cnt, int* __restrict__ indptr,
                        int* __restrict__ csum) {
  __shared__ int s[512];
  int t = threadIdx.x;
  int i = blockIdx.x * 512 + t;
  int v = (i < NN) ? cnt[i] : 0;
  s[t] = v; __syncthreads();
  for (int d = 1; d < 512; d <<= 1) {
    int x = (t >= d) ? s[t - d] : 0;
    __syncthreads();
    s[t] += x;
    __syncthreads();
  }
  if (i < NN) indptr[i] = s[t] - v;
  if (t == 511) csum[blockIdx.x] = s[t];
}

__global__ void k_scan2(const int* __restrict__ csum, int* __restrict__ coff) {
  __shared__ int s[128];
  int t = threadIdx.x;
  int v = (t < NCHUNK) ? csum[t] : 0;
  s[t] = v; __syncthreads();
  for (int d = 1; d < 128; d <<= 1) {
    int x = (t >= d) ? s[t - d] : 0;
    __syncthreads();
    s[t] += x;
    __syncthreads();
  }
  if (t < NCHUNK) coff[t] = s[t] - v;
}

__global__ void k_scan3(const int* __restrict__ coff, int* __restrict__ indptr,
                        int* __restrict__ cursor) {
  int i = blockIdx.x * 512 + threadIdx.x;
  if (i < NN) {
    int v = indptr[i] + coff[blockIdx.x];
    indptr[i] = v;
    cursor[i] = v;
  }
}

__global__ void k_fill(const int* __restrict__ src, const int* __restrict__ dst,
                       int* __restrict__ cursor, int* __restrict__ csr) {
  int e = blockIdx.x * 256 + threadIdx.x;
  if (e < EE) {
    int p = atomicAdd(&cursor[dst[e]], 1);
    csr[p] = src[e];
  }
}

// ---------------- weight transpose fp32 -> bf16 (256x256) ----------------
__global__ void k_transpose(const float* __restrict__ W, u16* __restrict__ WT) {
  __shared__ float tile[32][33];
  int bx = blockIdx.x & 7, by = blockIdx.x >> 3;
  int tx = threadIdx.x & 31, ty = threadIdx.x >> 5;
#pragma unroll
  for (int i = 0; i < 32; i += 8)
    tile[ty + i][tx] = W[(by * 32 + ty + i) * 256 + bx * 32 + tx];
  __syncthreads();
#pragma unroll
  for (int i = 0; i < 32; i += 8)
    WT[(bx * 32 + ty + i) * 256 + by * 32 + tx] = f2b(tile[tx][ty + i]);
}

// ---------------- two-pass column stats ----------------
__global__ void k_colsum_f32(const float* __restrict__ X, float* __restrict__ sum) {
  int t = threadIdx.x;
  float s = 0.f;
  for (int r = blockIdx.x; r < NN; r += gridDim.x) s += X[(size_t)r * 256 + t];
  atomicAdd(&sum[t], s);
}

__global__ void k_colvar_f32(const float* __restrict__ X, const float* __restrict__ sum,
                             float* __restrict__ varsum) {
  int t = threadIdx.x;
  float mu = sum[t] * (1.0f / NN);
  float q = 0.f;
  for (int r = blockIdx.x; r < NN; r += gridDim.x) {
    float d = X[(size_t)r * 256 + t] - mu;
    q += d * d;
  }
  atomicAdd(&varsum[t], q);
}

__global__ void k_colsum_bf(const u16* __restrict__ X, float* __restrict__ sum) {
  int t = threadIdx.x;
  float s = 0.f;
  for (int r = blockIdx.x; r < NN; r += gridDim.x) s += b2f(X[(size_t)r * 256 + t]);
  atomicAdd(&sum[t], s);
}

__global__ void k_colvar_bf(const u16* __restrict__ X, const float* __restrict__ sum,
                            float* __restrict__ varsum) {
  int t = threadIdx.x;
  float mu = sum[t] * (1.0f / NN);
  float q = 0.f;
  for (int r = blockIdx.x; r < NN; r += gridDim.x) {
    float d = b2f(X[(size_t)r * 256 + t]) - mu;
    q += d * d;
  }
  atomicAdd(&varsum[t], q);
}

// ---------------- BN apply to fp32 x -> bf16 xn ----------------
__global__ void k_bnx(const float* __restrict__ X, const float* __restrict__ sum,
                      const float* __restrict__ varsum, const float* __restrict__ g,
                      const float* __restrict__ b, u16* __restrict__ Y) {
  int t = threadIdx.x;
  float mu = sum[t] * (1.0f / NN);
  float var = fmaxf(varsum[t] * (1.0f / NN), 0.f);
  float rs = rsqrtf(var + 1e-5f);
  float ga = g[t] * rs;
  float be = b[t] - mu * ga;
  for (int r = blockIdx.x; r < NN; r += gridDim.x) {
    float v = X[(size_t)r * 256 + t];
    Y[(size_t)r * 256 + t] = f2b(v * ga + be);
  }
}

// ---------------- BN + relu + residual: h = relu(bn(m2)) + h ----------------
__global__ void k_bnres(const u16* __restrict__ M2, const float* __restrict__ sum,
                        const float* __restrict__ varsum, const float* __restrict__ g,
                        const float* __restrict__ b, u16* __restrict__ h) {
  int t = threadIdx.x;
  float mu = sum[t] * (1.0f / NN);
  float var = fmaxf(varsum[t] * (1.0f / NN), 0.f);
  float rs = rsqrtf(var + 1e-5f);
  float ga = g[t] * rs;
  float be = b[t] - mu * ga;
  for (int r = blockIdx.x; r < NN; r += gridDim.x) {
    float v = b2f(M2[(size_t)r * 256 + t]) * ga + be;
    v = fmaxf(v, 0.f);
    float hp = b2f(h[(size_t)r * 256 + t]);
    h[(size_t)r * 256 + t] = f2b(v + hp);
  }
}

// ---------------- aggregation: out[n] = h[n] + sum_{s in N(n)} h[s] ----------------
__global__ void k_agg(const u16* __restrict__ h, const int* __restrict__ indptr,
                      const int* __restrict__ cnt, const int* __restrict__ csr,
                      u16* __restrict__ out) {
  int w = threadIdx.x >> 6, l = threadIdx.x & 63;
  int node = blockIdx.x * 4 + w;
  if (node >= NN) return;
  int beg = indptr[node], deg = cnt[node];
  int c = l * 4;
  ushort4 v = *(const ushort4*)&h[(size_t)node * 256 + c];
  float a0 = b2f(v.x), a1 = b2f(v.y), a2 = b2f(v.z), a3 = b2f(v.w);
  for (int i = 0; i < deg; ++i) {
    int s = csr[beg + i];
    ushort4 u = *(const ushort4*)&h[(size_t)s * 256 + c];
    a0 += b2f(u.x); a1 += b2f(u.y); a2 += b2f(u.z); a3 += b2f(u.w);
  }
  ushort4 o;
  o.x = f2b(a0); o.y = f2b(a1); o.z = f2b(a2); o.w = f2b(a3);
  *(ushort4*)&out[(size_t)node * 256 + c] = o;
}

// ---------------- GEMM (H1 C/D mapping, probe-confirmed) ----------------
__global__ __launch_bounds__(256) void k_gemm(const u16* __restrict__ A,
                                              const u16* __restrict__ BT,
                                              const float* __restrict__ bias,
                                              u16* __restrict__ C, int relu) {
  __shared__ __align__(16) u16 As[128 * LDSW];
  __shared__ __align__(16) u16 Bs[128 * LDSW];
  int tid = threadIdx.x;
  int bid = blockIdx.x;
  int tn = bid & 1, tm = bid >> 1;
  int w = tid >> 6, l = tid & 63;
  int wr = (w >> 1) * 64, wc = (w & 1) * 64;

  const u16* Ag = A + (size_t)tm * 128 * 256;
  const u16* Bg = BT + (size_t)tn * 128 * 256;

  f32x4 zz; zz[0] = 0.f; zz[1] = 0.f; zz[2] = 0.f; zz[3] = 0.f;
  f32x4 acc[4][4];
#pragma unroll
  for (int m = 0; m < 4; ++m)
#pragma unroll
    for (int n = 0; n < 4; ++n) acc[m][n] = zz;

  int r0 = w * 16 + (l >> 2);
  int r1 = r0 + 64;
  int kc = (l & 3) * 8;
  int w0 = r0 * LDSW + (l & 3) * 8;
  int w1 = r1 * LDSW + (l & 3) * 8;

  short8 pa0 = *(const short8*)(Ag + (size_t)r0 * 256 + kc);
  short8 pa1 = *(const short8*)(Ag + (size_t)r1 * 256 + kc);
  short8 pb0 = *(const short8*)(Bg + (size_t)r0 * 256 + kc);
  short8 pb1 = *(const short8*)(Bg + (size_t)r1 * 256 + kc);

  for (int kk = 0; kk < 8; ++kk) {
    *(short8*)&As[w0] = pa0;
    *(short8*)&As[w1] = pa1;
    *(short8*)&Bs[w0] = pb0;
    *(short8*)&Bs[w1] = pb1;
    if (kk < 7) {
      int k0 = (kk + 1) * 32 + kc;
      pa0 = *(const short8*)(Ag + (size_t)r0 * 256 + k0);
      pa1 = *(const short8*)(Ag + (size_t)r1 * 256 + k0);
      pb0 = *(const short8*)(Bg + (size_t)r0 * 256 + k0);
      pb1 = *(const short8*)(Bg + (size_t)r1 * 256 + k0);
    }
    __syncthreads();
    short8 af[4], bfr[4];
#pragma unroll
    for (int m = 0; m < 4; ++m) {
      int row = wr + m * 16 + (l & 15);
      af[m] = *(const short8*)&As[row * LDSW + (l >> 4) * 8];
    }
#pragma unroll
    for (int n = 0; n < 4; ++n) {
      int row = wc + n * 16 + (l & 15);
      bfr[n] = *(const short8*)&Bs[row * LDSW + (l >> 4) * 8];
    }
#pragma unroll
    for (int m = 0; m < 4; ++m)
#pragma unroll
      for (int n = 0; n < 4; ++n)
        acc[m][n] = __builtin_amdgcn_mfma_f32_16x16x32_bf16(af[m], bfr[n], acc[m][n], 0, 0, 0);
    __syncthreads();
  }

  int colb = tn * 128 + wc;
  int rowb = tm * 128 + wr + (l >> 4) * 4;
#pragma unroll
  for (int n = 0; n < 4; ++n) {
    int c = colb + n * 16 + (l & 15);
    float bz = bias[c];
#pragma unroll
    for (int m = 0; m < 4; ++m) {
      int r = rowb + m * 16;
#pragma unroll
      for (int i = 0; i < 4; ++i) {
        float v = acc[m][n][i] + bz;
        if (relu) v = fmaxf(v, 0.f);
        C[(size_t)(r + i) * 256 + c] = f2b(v);
      }
    }
  }
}

// ---------------- pooling (batch sorted) ----------------
__global__ void k_pool(const u16* __restrict__ h, const int* __restrict__ batch,
                       float* __restrict__ pooled, int* __restrict__ gcnt) {
  __shared__ int bg[128];
  int t = threadIdx.x;
  int r0 = blockIdx.x * 128;
  int rend = min(r0 + 128, NN);
  if (r0 >= NN) return;
  if (t < 128 && r0 + t < NN) bg[t] = batch[r0 + t];
  __syncthreads();
  float a = 0.f;
  int cur = bg[0];
  int cl = 0;
  for (int r = r0; r < rend; ++r) {
    int g = bg[r - r0];
    if (g != cur) {
      atomicAdd(&pooled[(size_t)cur * 256 + t], a);
      if (t == 0) atomicAdd(&gcnt[cur], cl);
      a = 0.f; cl = 0; cur = g;
    }
    a += b2f(h[(size_t)r * 256 + t]);
    cl++;
  }
  atomicAdd(&pooled[(size_t)cur * 256 + t], a);
  if (t == 0) atomicAdd(&gcnt[cur], cl);
}

// ---------------- head: embed + logits (FP32 out — the R7 fix) ----------------
__global__ void k_head(const float* __restrict__ pooled, const int* __restrict__ gcnt,
                       const float* __restrict__ predW, const float* __restrict__ predb,
                       float* __restrict__ out) {
  __shared__ float pm[256];
  int g = blockIdx.x, t = threadIdx.x;
  float c = fmaxf((float)gcnt[g], 1.0f);
  float v = pooled[(size_t)g * 256 + t] / c;
  pm[t] = v;
  out[(size_t)g * 256 + t] = v;               // embed, fp32
  __syncthreads();
  if (t < NOTESD) {
    float acc = predb[t];
    for (int k = 0; k < 256; ++k)
      acc += pm[k] * predW[k * NOTESD + t];
    out[(size_t)GG * 256 + (size_t)g * NOTESD + t] = acc;  // logits, fp32
  }
}

extern "C" void kernel_launch(void* const* d_in, const int* in_sizes, int n_in,
                              void* d_out, int out_size, void* d_ws, size_t ws_size,
                              hipStream_t stream) {
  const float* x     = (const float*)d_in[0];
  const int*   ei    = (const int*)d_in[1];
  const int*   batch = (const int*)d_in[2];
  const float* fng   = (const float*)d_in[3];
  const float* fnb   = (const float*)d_in[4];
  const float* projW = (const float*)d_in[5];
  const float* projb = (const float*)d_in[6];
  const float* W1    = (const float*)d_in[7];
  const float* b1    = (const float*)d_in[8];
  const float* W2    = (const float*)d_in[9];
  const float* b2    = (const float*)d_in[10];
  const float* bng   = (const float*)d_in[11];
  const float* bnb   = (const float*)d_in[12];
  const float* predW = (const float*)d_in[13];
  const float* predb = (const float*)d_in[14];
  float* out = (float*)d_out;

  char* ws = (char*)d_ws;
  size_t off = 0;
  auto alloc = [&](size_t b) { size_t o = off; off += (b + 255) & ~(size_t)255; return o; };
  u16* h    = (u16*)(ws + alloc((size_t)MPAD * 256 * 2));
  u16* bufA = (u16*)(ws + alloc((size_t)MPAD * 256 * 2));
  u16* bufB = (u16*)(ws + alloc((size_t)MPAD * 256 * 2));
  u16* wt   = (u16*)(ws + alloc((size_t)9 * 65536 * 2));
  int* cnt    = (int*)(ws + alloc((size_t)NN * 4));
  int* indptr = (int*)(ws + alloc((size_t)NN * 4));
  int* cursor = (int*)(ws + alloc((size_t)NN * 4));
  int* csum   = (int*)(ws + alloc(512));
  int* coff   = (int*)(ws + alloc(512));
  int* csr    = (int*)(ws + alloc((size_t)EE * 4));
  float* bnsum  = (float*)(ws + alloc(1024));
  float* bnvar  = (float*)(ws + alloc(1024));
  float* pooled = (float*)(ws + alloc((size_t)GG * 256 * 4));
  int* gcnt     = (int*)(ws + alloc((size_t)GG * 4));

  const int* srcI = ei;
  const int* dstI = ei + EE;

  // CSR build
  hipMemsetAsync(cnt, 0, (size_t)NN * 4, stream);
  k_hist<<<(EE + 255) / 256, 256, 0, stream>>>(dstI, cnt);
  k_scan1<<<NCHUNK, 512, 0, stream>>>(cnt, indptr, csum);
  k_scan2<<<1, 128, 0, stream>>>(csum, coff);
  k_scan3<<<NCHUNK, 512, 0, stream>>>(coff, indptr, cursor);
  k_fill<<<(EE + 255) / 256, 256, 0, stream>>>(srcI, dstI, cursor, csr);

  // weight transposes (fp32 -> bf16)
  k_transpose<<<64, 256, 0, stream>>>(projW, wt);
  for (int l = 0; l < 4; ++l) {
    k_transpose<<<64, 256, 0, stream>>>(W1 + (size_t)l * 65536, wt + (size_t)(1 + l) * 65536);
    k_transpose<<<64, 256, 0, stream>>>(W2 + (size_t)l * 65536, wt + (size_t)(5 + l) * 65536);
  }

  // feature BN (two-pass) -> bufA
  hipMemsetAsync(bnsum, 0, 1024, stream);
  hipMemsetAsync(bnvar, 0, 1024, stream);
  hipMemsetAsync(bufA + (size_t)NN * 256, 0, (size_t)(MPAD - NN) * 256 * 2, stream);
  k_colsum_f32<<<512, 256, 0, stream>>>(x, bnsum);
  k_colvar_f32<<<512, 256, 0, stream>>>(x, bnsum, bnvar);
  k_bnx<<<512, 256, 0, stream>>>(x, bnsum, bnvar, fng, fnb, bufA);

  // projection: h = relu(xn @ projW + projb)
  k_gemm<<<TM_TILES * 2, 256, 0, stream>>>(bufA, wt, projb, h, 1);

  for (int l = 0; l < 4; ++l) {
    k_agg<<<(NN + 3) / 4, 256, 0, stream>>>(h, indptr, cnt, csr, bufA);
    k_gemm<<<TM_TILES * 2, 256, 0, stream>>>(bufA, wt + (size_t)(1 + l) * 65536,
                                             b1 + (size_t)l * 256, bufB, 1);
    k_gemm<<<TM_TILES * 2, 256, 0, stream>>>(bufB, wt + (size_t)(5 + l) * 65536,
                                             b2 + (size_t)l * 256, bufA, 0);
    hipMemsetAsync(bnsum, 0, 1024, stream);
    hipMemsetAsync(bnvar, 0, 1024, stream);
    k_colsum_bf<<<512, 256, 0, stream>>>(bufA, bnsum);
    k_colvar_bf<<<512, 256, 0, stream>>>(bufA, bnsum, bnvar);
    k_bnres<<<512, 256, 0, stream>>>(bufA, bnsum, bnvar, bng + (size_t)l * 256,
                                     bnb + (size_t)l * 256, h);
  }

  // readout
  hipMemsetAsync(pooled, 0, (size_t)GG * 256 * 4, stream);
  hipMemsetAsync(gcnt, 0, (size_t)GG * 4, stream);
  k_pool<<<(NN + 127) / 128, 256, 0, stream>>>(h, batch, pooled, gcnt);
  k_head<<<GG, 256, 0, stream>>>(pooled, gcnt, predW, predb, out);
}

// Round 9
// 835.606 us; speedup vs baseline: 1.4093x; 1.4093x over previous
//
#include <hip/hip_runtime.h>
#include <hip/hip_bf16.h>
#include <stdint.h>

#define NN 50000
#define EE 800000
#define GG 64
#define NOTESD 128
#define MPAD 50048
#define TM_TILES 391
#define NCHUNK 98
#define LDSW 40

typedef unsigned short u16;
typedef __attribute__((ext_vector_type(8))) short short8;
typedef __attribute__((ext_vector_type(4))) float f32x4;

__device__ __forceinline__ float b2f(u16 u) {
  union { uint32_t i; float f; } x; x.i = ((uint32_t)u) << 16; return x.f;
}
__device__ __forceinline__ u16 f2b(float f) {
  __hip_bfloat16 h = __float2bfloat16(f);
  return *reinterpret_cast<u16*>(&h);
}

// ---------------- CSR build ----------------
__global__ void k_hist(const int* __restrict__ dst, int* __restrict__ cnt) {
  int e = blockIdx.x * 256 + threadIdx.x;
  if (e < EE) atomicAdd(&cnt[dst[e]], 1);
}

__global__ void k_scan1(const int* __restrict__ cnt, int* __restrict__ indptr,
                        int* __restrict__ csum) {
  __shared__ int s[512];
  int t = threadIdx.x;
  int i = blockIdx.x * 512 + t;
  int v = (i < NN) ? cnt[i] : 0;
  s[t] = v; __syncthreads();
  for (int d = 1; d < 512; d <<= 1) {
    int x = (t >= d) ? s[t - d] : 0;
    __syncthreads();
    s[t] += x;
    __syncthreads();
  }
  if (i < NN) indptr[i] = s[t] - v;
  if (t == 511) csum[blockIdx.x] = s[t];
}

__global__ void k_scan2(const int* __restrict__ csum, int* __restrict__ coff) {
  __shared__ int s[128];
  int t = threadIdx.x;
  int v = (t < NCHUNK) ? csum[t] : 0;
  s[t] = v; __syncthreads();
  for (int d = 1; d < 128; d <<= 1) {
    int x = (t >= d) ? s[t - d] : 0;
    __syncthreads();
    s[t] += x;
    __syncthreads();
  }
  if (t < NCHUNK) coff[t] = s[t] - v;
}

__global__ void k_scan3(const int* __restrict__ coff, int* __restrict__ indptr,
                        int* __restrict__ cursor) {
  int i = blockIdx.x * 512 + threadIdx.x;
  if (i < NN) {
    int v = indptr[i] + coff[blockIdx.x];
    indptr[i] = v;
    cursor[i] = v;
  }
}

__global__ void k_fill(const int* __restrict__ src, const int* __restrict__ dst,
                       int* __restrict__ cursor, int* __restrict__ csr) {
  int e = blockIdx.x * 256 + threadIdx.x;
  if (e < EE) {
    int p = atomicAdd(&cursor[dst[e]], 1);
    csr[p] = src[e];
  }
}

// ---------------- weight transpose fp32 -> bf16 (256x256) ----------------
__global__ void k_transpose(const float* __restrict__ W, u16* __restrict__ WT) {
  __shared__ float tile[32][33];
  int bx = blockIdx.x & 7, by = blockIdx.x >> 3;
  int tx = threadIdx.x & 31, ty = threadIdx.x >> 5;
#pragma unroll
  for (int i = 0; i < 32; i += 8)
    tile[ty + i][tx] = W[(by * 32 + ty + i) * 256 + bx * 32 + tx];
  __syncthreads();
#pragma unroll
  for (int i = 0; i < 32; i += 8)
    WT[(bx * 32 + ty + i) * 256 + by * 32 + tx] = f2b(tile[tx][ty + i]);
}

// ---------------- one-pass column stats for fp32 x (mu~0: no cancellation risk) ----------------
__global__ void k_colstats_f32(const float* __restrict__ X, float* __restrict__ sum,
                               float* __restrict__ sq) {
  int t = threadIdx.x;
  float s = 0.f, q = 0.f;
  for (int r = blockIdx.x; r < NN; r += gridDim.x) {
    float v = X[(size_t)r * 256 + t];
    s += v; q += v * v;
  }
  atomicAdd(&sum[t], s);
  atomicAdd(&sq[t], q);
}

// ---------------- BN apply to fp32 x -> bf16 xn ----------------
__global__ void k_bnx(const float* __restrict__ X, const float* __restrict__ sum,
                      const float* __restrict__ sq, const float* __restrict__ g,
                      const float* __restrict__ b, u16* __restrict__ Y) {
  int t = threadIdx.x;
  float mu = sum[t] * (1.0f / NN);
  float var = fmaxf(sq[t] * (1.0f / NN) - mu * mu, 0.f);
  float rs = rsqrtf(var + 1e-5f);
  float ga = g[t] * rs;
  float be = b[t] - mu * ga;
  for (int r = blockIdx.x; r < NN; r += gridDim.x) {
    float v = X[(size_t)r * 256 + t];
    Y[(size_t)r * 256 + t] = f2b(v * ga + be);
  }
}

// ---------------- BN + relu + residual: h = relu(bn(m2)) + h ----------------
// stats come fused from GEMM2 epilogue (fp32 pre-rounding values)
__global__ void k_bnres(const u16* __restrict__ M2, const float* __restrict__ sum,
                        const float* __restrict__ sq, const float* __restrict__ g,
                        const float* __restrict__ b, u16* __restrict__ h) {
  int t = threadIdx.x;
  float mu = sum[t] * (1.0f / NN);
  float var = fmaxf(sq[t] * (1.0f / NN) - mu * mu, 0.f);
  float rs = rsqrtf(var + 1e-5f);
  float ga = g[t] * rs;
  float be = b[t] - mu * ga;
  for (int r = blockIdx.x; r < NN; r += gridDim.x) {
    float v = b2f(M2[(size_t)r * 256 + t]) * ga + be;
    v = fmaxf(v, 0.f);
    float hp = b2f(h[(size_t)r * 256 + t]);
    h[(size_t)r * 256 + t] = f2b(v + hp);
  }
}

// ---------------- aggregation: out[n] = h[n] + sum_{s in N(n)} h[s] ----------------
// 8x-unrolled gather: 8 independent 512B row loads in flight per wave (latency-bound fix)
__global__ void k_agg(const u16* __restrict__ h, const int* __restrict__ indptr,
                      const int* __restrict__ cnt, const int* __restrict__ csr,
                      u16* __restrict__ out) {
  int w = threadIdx.x >> 6, l = threadIdx.x & 63;
  int node = blockIdx.x * 4 + w;
  if (node >= NN) return;
  int beg = indptr[node], deg = cnt[node];
  const ushort4* hv = (const ushort4*)h + l;   // row r: hv[r*64]
  ushort4 v = hv[(size_t)node * 64];
  float a0 = b2f(v.x), a1 = b2f(v.y), a2 = b2f(v.z), a3 = b2f(v.w);
  int i = 0;
  for (; i + 8 <= deg; i += 8) {
    int s0 = csr[beg + i + 0], s1 = csr[beg + i + 1];
    int s2 = csr[beg + i + 2], s3 = csr[beg + i + 3];
    int s4 = csr[beg + i + 4], s5 = csr[beg + i + 5];
    int s6 = csr[beg + i + 6], s7 = csr[beg + i + 7];
    ushort4 u0 = hv[(size_t)s0 * 64], u1 = hv[(size_t)s1 * 64];
    ushort4 u2 = hv[(size_t)s2 * 64], u3 = hv[(size_t)s3 * 64];
    ushort4 u4 = hv[(size_t)s4 * 64], u5 = hv[(size_t)s5 * 64];
    ushort4 u6 = hv[(size_t)s6 * 64], u7 = hv[(size_t)s7 * 64];
    a0 += b2f(u0.x) + b2f(u1.x) + b2f(u2.x) + b2f(u3.x)
        + b2f(u4.x) + b2f(u5.x) + b2f(u6.x) + b2f(u7.x);
    a1 += b2f(u0.y) + b2f(u1.y) + b2f(u2.y) + b2f(u3.y)
        + b2f(u4.y) + b2f(u5.y) + b2f(u6.y) + b2f(u7.y);
    a2 += b2f(u0.z) + b2f(u1.z) + b2f(u2.z) + b2f(u3.z)
        + b2f(u4.z) + b2f(u5.z) + b2f(u6.z) + b2f(u7.z);
    a3 += b2f(u0.w) + b2f(u1.w) + b2f(u2.w) + b2f(u3.w)
        + b2f(u4.w) + b2f(u5.w) + b2f(u6.w) + b2f(u7.w);
  }
  for (; i + 4 <= deg; i += 4) {
    int s0 = csr[beg + i + 0], s1 = csr[beg + i + 1];
    int s2 = csr[beg + i + 2], s3 = csr[beg + i + 3];
    ushort4 u0 = hv[(size_t)s0 * 64], u1 = hv[(size_t)s1 * 64];
    ushort4 u2 = hv[(size_t)s2 * 64], u3 = hv[(size_t)s3 * 64];
    a0 += b2f(u0.x) + b2f(u1.x) + b2f(u2.x) + b2f(u3.x);
    a1 += b2f(u0.y) + b2f(u1.y) + b2f(u2.y) + b2f(u3.y);
    a2 += b2f(u0.z) + b2f(u1.z) + b2f(u2.z) + b2f(u3.z);
    a3 += b2f(u0.w) + b2f(u1.w) + b2f(u2.w) + b2f(u3.w);
  }
  for (; i < deg; ++i) {
    int s = csr[beg + i];
    ushort4 u = hv[(size_t)s * 64];
    a0 += b2f(u.x); a1 += b2f(u.y); a2 += b2f(u.z); a3 += b2f(u.w);
  }
  ushort4 o;
  o.x = f2b(a0); o.y = f2b(a1); o.z = f2b(a2); o.w = f2b(a3);
  *((ushort4*)out + (size_t)node * 64 + l) = o;
}

// ---------------- GEMM: C = act(A @ W + bias); optional fused column stats ----------------
__global__ __launch_bounds__(256) void k_gemm(const u16* __restrict__ A,
                                              const u16* __restrict__ BT,
                                              const float* __restrict__ bias,
                                              u16* __restrict__ C, int relu,
                                              float* __restrict__ csum,
                                              float* __restrict__ csq, int dostats) {
  __shared__ __align__(16) u16 As[128 * LDSW];
  __shared__ __align__(16) u16 Bs[128 * LDSW];
  int tid = threadIdx.x;
  int bid = blockIdx.x;
  int tn = bid & 1, tm = bid >> 1;
  int w = tid >> 6, l = tid & 63;
  int wr = (w >> 1) * 64, wc = (w & 1) * 64;

  const u16* Ag = A + (size_t)tm * 128 * 256;
  const u16* Bg = BT + (size_t)tn * 128 * 256;

  f32x4 zz; zz[0] = 0.f; zz[1] = 0.f; zz[2] = 0.f; zz[3] = 0.f;
  f32x4 acc[4][4];
#pragma unroll
  for (int m = 0; m < 4; ++m)
#pragma unroll
    for (int n = 0; n < 4; ++n) acc[m][n] = zz;

  int r0 = w * 16 + (l >> 2);
  int r1 = r0 + 64;
  int kc = (l & 3) * 8;
  int w0 = r0 * LDSW + (l & 3) * 8;
  int w1 = r1 * LDSW + (l & 3) * 8;

  short8 pa0 = *(const short8*)(Ag + (size_t)r0 * 256 + kc);
  short8 pa1 = *(const short8*)(Ag + (size_t)r1 * 256 + kc);
  short8 pb0 = *(const short8*)(Bg + (size_t)r0 * 256 + kc);
  short8 pb1 = *(const short8*)(Bg + (size_t)r1 * 256 + kc);

  for (int kk = 0; kk < 8; ++kk) {
    *(short8*)&As[w0] = pa0;
    *(short8*)&As[w1] = pa1;
    *(short8*)&Bs[w0] = pb0;
    *(short8*)&Bs[w1] = pb1;
    if (kk < 7) {
      int k0 = (kk + 1) * 32 + kc;
      pa0 = *(const short8*)(Ag + (size_t)r0 * 256 + k0);
      pa1 = *(const short8*)(Ag + (size_t)r1 * 256 + k0);
      pb0 = *(const short8*)(Bg + (size_t)r0 * 256 + k0);
      pb1 = *(const short8*)(Bg + (size_t)r1 * 256 + k0);
    }
    __syncthreads();
    short8 af[4], bfr[4];
#pragma unroll
    for (int m = 0; m < 4; ++m) {
      int row = wr + m * 16 + (l & 15);
      af[m] = *(const short8*)&As[row * LDSW + (l >> 4) * 8];
    }
#pragma unroll
    for (int n = 0; n < 4; ++n) {
      int row = wc + n * 16 + (l & 15);
      bfr[n] = *(const short8*)&Bs[row * LDSW + (l >> 4) * 8];
    }
#pragma unroll
    for (int m = 0; m < 4; ++m)
#pragma unroll
      for (int n = 0; n < 4; ++n)
        acc[m][n] = __builtin_amdgcn_mfma_f32_16x16x32_bf16(af[m], bfr[n], acc[m][n], 0, 0, 0);
    __syncthreads();
  }

  int colb = tn * 128 + wc;
  int rowb = tm * 128 + wr + (l >> 4) * 4;
#pragma unroll
  for (int n = 0; n < 4; ++n) {
    int c = colb + n * 16 + (l & 15);
    float bz = bias[c];
    float s = 0.f, q = 0.f;
#pragma unroll
    for (int m = 0; m < 4; ++m) {
      int r = rowb + m * 16;
#pragma unroll
      for (int i = 0; i < 4; ++i) {
        float v = acc[m][n][i] + bz;
        if (relu) v = fmaxf(v, 0.f);
        C[(size_t)(r + i) * 256 + c] = f2b(v);
        if (dostats && (r + i) < NN) { s += v; q += v * v; }
      }
    }
    if (dostats) {
      s += __shfl_xor(s, 16); s += __shfl_xor(s, 32);
      q += __shfl_xor(q, 16); q += __shfl_xor(q, 32);
      if ((l >> 4) == 0) {
        atomicAdd(&csum[c], s);
        atomicAdd(&csq[c], q);
      }
    }
  }
}

// ---------------- pooling (batch sorted) ----------------
__global__ void k_pool(const u16* __restrict__ h, const int* __restrict__ batch,
                       float* __restrict__ pooled, int* __restrict__ gcnt) {
  __shared__ int bg[128];
  int t = threadIdx.x;
  int r0 = blockIdx.x * 128;
  int rend = min(r0 + 128, NN);
  if (r0 >= NN) return;
  if (t < 128 && r0 + t < NN) bg[t] = batch[r0 + t];
  __syncthreads();
  float a = 0.f;
  int cur = bg[0];
  int cl = 0;
  for (int r = r0; r < rend; ++r) {
    int g = bg[r - r0];
    if (g != cur) {
      atomicAdd(&pooled[(size_t)cur * 256 + t], a);
      if (t == 0) atomicAdd(&gcnt[cur], cl);
      a = 0.f; cl = 0; cur = g;
    }
    a += b2f(h[(size_t)r * 256 + t]);
    cl++;
  }
  atomicAdd(&pooled[(size_t)cur * 256 + t], a);
  if (t == 0) atomicAdd(&gcnt[cur], cl);
}

// ---------------- head: embed + logits (fp32 out) ----------------
__global__ void k_head(const float* __restrict__ pooled, const int* __restrict__ gcnt,
                       const float* __restrict__ predW, const float* __restrict__ predb,
                       float* __restrict__ out) {
  __shared__ float pm[256];
  int g = blockIdx.x, t = threadIdx.x;
  float c = fmaxf((float)gcnt[g], 1.0f);
  float v = pooled[(size_t)g * 256 + t] / c;
  pm[t] = v;
  out[(size_t)g * 256 + t] = v;
  __syncthreads();
  if (t < NOTESD) {
    float acc = predb[t];
    for (int k = 0; k < 256; ++k)
      acc += pm[k] * predW[k * NOTESD + t];
    out[(size_t)GG * 256 + (size_t)g * NOTESD + t] = acc;
  }
}

extern "C" void kernel_launch(void* const* d_in, const int* in_sizes, int n_in,
                              void* d_out, int out_size, void* d_ws, size_t ws_size,
                              hipStream_t stream) {
  const float* x     = (const float*)d_in[0];
  const int*   ei    = (const int*)d_in[1];
  const int*   batch = (const int*)d_in[2];
  const float* fng   = (const float*)d_in[3];
  const float* fnb   = (const float*)d_in[4];
  const float* projW = (const float*)d_in[5];
  const float* projb = (const float*)d_in[6];
  const float* W1    = (const float*)d_in[7];
  const float* b1    = (const float*)d_in[8];
  const float* W2    = (const float*)d_in[9];
  const float* b2    = (const float*)d_in[10];
  const float* bng   = (const float*)d_in[11];
  const float* bnb   = (const float*)d_in[12];
  const float* predW = (const float*)d_in[13];
  const float* predb = (const float*)d_in[14];
  float* out = (float*)d_out;

  char* ws = (char*)d_ws;
  size_t off = 0;
  auto alloc = [&](size_t b) { size_t o = off; off += (b + 255) & ~(size_t)255; return o; };
  u16* h    = (u16*)(ws + alloc((size_t)MPAD * 256 * 2));
  u16* bufA = (u16*)(ws + alloc((size_t)MPAD * 256 * 2));
  u16* bufB = (u16*)(ws + alloc((size_t)MPAD * 256 * 2));
  u16* wt   = (u16*)(ws + alloc((size_t)9 * 65536 * 2));
  int* cnt    = (int*)(ws + alloc((size_t)NN * 4));
  int* indptr = (int*)(ws + alloc((size_t)NN * 4));
  int* cursor = (int*)(ws + alloc((size_t)NN * 4));
  int* csum   = (int*)(ws + alloc(512));
  int* coff   = (int*)(ws + alloc(512));
  int* csr    = (int*)(ws + alloc((size_t)EE * 4));
  float* bnsum  = (float*)(ws + alloc(1024));
  float* bnvar  = (float*)(ws + alloc(1024));
  float* pooled = (float*)(ws + alloc((size_t)GG * 256 * 4));
  int* gcnt     = (int*)(ws + alloc((size_t)GG * 4));

  const int* srcI = ei;
  const int* dstI = ei + EE;

  // CSR build
  hipMemsetAsync(cnt, 0, (size_t)NN * 4, stream);
  k_hist<<<(EE + 255) / 256, 256, 0, stream>>>(dstI, cnt);
  k_scan1<<<NCHUNK, 512, 0, stream>>>(cnt, indptr, csum);
  k_scan2<<<1, 128, 0, stream>>>(csum, coff);
  k_scan3<<<NCHUNK, 512, 0, stream>>>(coff, indptr, cursor);
  k_fill<<<(EE + 255) / 256, 256, 0, stream>>>(srcI, dstI, cursor, csr);

  // weight transposes (fp32 -> bf16)
  k_transpose<<<64, 256, 0, stream>>>(projW, wt);
  for (int l = 0; l < 4; ++l) {
    k_transpose<<<64, 256, 0, stream>>>(W1 + (size_t)l * 65536, wt + (size_t)(1 + l) * 65536);
    k_transpose<<<64, 256, 0, stream>>>(W2 + (size_t)l * 65536, wt + (size_t)(5 + l) * 65536);
  }

  // feature BN (one fused stats pass; x has mu~0, no cancellation) -> bufA
  hipMemsetAsync(bnsum, 0, 1024, stream);
  hipMemsetAsync(bnvar, 0, 1024, stream);
  hipMemsetAsync(bufA + (size_t)NN * 256, 0, (size_t)(MPAD - NN) * 256 * 2, stream);
  k_colstats_f32<<<512, 256, 0, stream>>>(x, bnsum, bnvar);
  k_bnx<<<512, 256, 0, stream>>>(x, bnsum, bnvar, fng, fnb, bufA);

  // projection: h = relu(xn @ projW + projb)
  k_gemm<<<TM_TILES * 2, 256, 0, stream>>>(bufA, wt, projb, h, 1, nullptr, nullptr, 0);

  for (int l = 0; l < 4; ++l) {
    k_agg<<<(NN + 3) / 4, 256, 0, stream>>>(h, indptr, cnt, csr, bufA);
    k_gemm<<<TM_TILES * 2, 256, 0, stream>>>(bufA, wt + (size_t)(1 + l) * 65536,
                                             b1 + (size_t)l * 256, bufB, 1, nullptr, nullptr, 0);
    // GEMM2 with fused column stats (fp32 pre-rounding values, rows < NN only)
    hipMemsetAsync(bnsum, 0, 1024, stream);
    hipMemsetAsync(bnvar, 0, 1024, stream);
    k_gemm<<<TM_TILES * 2, 256, 0, stream>>>(bufB, wt + (size_t)(5 + l) * 65536,
                                             b2 + (size_t)l * 256, bufA, 0, bnsum, bnvar, 1);
    k_bnres<<<512, 256, 0, stream>>>(bufA, bnsum, bnvar, bng + (size_t)l * 256,
                                     bnb + (size_t)l * 256, h);
  }

  // readout
  hipMemsetAsync(pooled, 0, (size_t)GG * 256 * 4, stream);
  hipMemsetAsync(gcnt, 0, (size_t)GG * 4, stream);
  k_pool<<<(NN + 127) / 128, 256, 0, stream>>>(h, batch, pooled, gcnt);
  k_head<<<GG, 256, 0, stream>>>(pooled, gcnt, predW, predb, out);
}

// Round 10
// 807.659 us; speedup vs baseline: 1.4581x; 1.0346x over previous
//
#include <hip/hip_runtime.h>
#include <hip/hip_bf16.h>
#include <stdint.h>

#define NN 50000
#define EE 800000
#define GG 64
#define NOTESD 128
#define MPAD 50048
#define TM_TILES 391
#define NCHUNK 98
#define LDSW 40

typedef unsigned short u16;
typedef __attribute__((ext_vector_type(8))) short short8;
typedef __attribute__((ext_vector_type(4))) float f32x4;

__device__ __forceinline__ float b2f(u16 u) {
  union { uint32_t i; float f; } x; x.i = ((uint32_t)u) << 16; return x.f;
}
__device__ __forceinline__ u16 f2b(float f) {
  __hip_bfloat16 h = __float2bfloat16(f);
  return *reinterpret_cast<u16*>(&h);
}

// ---------------- CSR build ----------------
__global__ void k_hist(const int* __restrict__ dst, int* __restrict__ cnt) {
  int e = blockIdx.x * 256 + threadIdx.x;
  if (e < EE) atomicAdd(&cnt[dst[e]], 1);
}

__global__ void k_scan1(const int* __restrict__ cnt, int* __restrict__ indptr,
                        int* __restrict__ csum) {
  __shared__ int s[512];
  int t = threadIdx.x;
  int i = blockIdx.x * 512 + t;
  int v = (i < NN) ? cnt[i] : 0;
  s[t] = v; __syncthreads();
  for (int d = 1; d < 512; d <<= 1) {
    int x = (t >= d) ? s[t - d] : 0;
    __syncthreads();
    s[t] += x;
    __syncthreads();
  }
  if (i < NN) indptr[i] = s[t] - v;
  if (t == 511) csum[blockIdx.x] = s[t];
}

__global__ void k_scan2(const int* __restrict__ csum, int* __restrict__ coff) {
  __shared__ int s[128];
  int t = threadIdx.x;
  int v = (t < NCHUNK) ? csum[t] : 0;
  s[t] = v; __syncthreads();
  for (int d = 1; d < 128; d <<= 1) {
    int x = (t >= d) ? s[t - d] : 0;
    __syncthreads();
    s[t] += x;
    __syncthreads();
  }
  if (t < NCHUNK) coff[t] = s[t] - v;
}

__global__ void k_scan3(const int* __restrict__ coff, int* __restrict__ indptr,
                        int* __restrict__ cursor) {
  int i = blockIdx.x * 512 + threadIdx.x;
  if (i < NN) {
    int v = indptr[i] + coff[blockIdx.x];
    indptr[i] = v;
    cursor[i] = v;
  }
}

__global__ void k_fill(const int* __restrict__ src, const int* __restrict__ dst,
                       int* __restrict__ cursor, int* __restrict__ csr) {
  int e = blockIdx.x * 256 + threadIdx.x;
  if (e < EE) {
    int p = atomicAdd(&cursor[dst[e]], 1);
    csr[p] = src[e];
  }
}

// ---------------- all 9 weight transposes (fp32 -> bf16, 256x256 each) ----------------
__global__ void k_transpose_all(const float* __restrict__ proj, const float* __restrict__ W1,
                                const float* __restrict__ W2, u16* __restrict__ WT) {
  __shared__ float tile[32][33];
  int mat = blockIdx.x >> 6;
  int bid = blockIdx.x & 63;
  const float* W = (mat == 0) ? proj
                 : (mat <= 4) ? W1 + (size_t)(mat - 1) * 65536
                              : W2 + (size_t)(mat - 5) * 65536;
  u16* dst = WT + (size_t)mat * 65536;
  int bx = bid & 7, by = bid >> 3;
  int tx = threadIdx.x & 31, ty = threadIdx.x >> 5;
#pragma unroll
  for (int i = 0; i < 32; i += 8)
    tile[ty + i][tx] = W[(by * 32 + ty + i) * 256 + bx * 32 + tx];
  __syncthreads();
#pragma unroll
  for (int i = 0; i < 32; i += 8)
    dst[(bx * 32 + ty + i) * 256 + by * 32 + tx] = f2b(tile[tx][ty + i]);
}

// ---------------- one-pass column stats for fp32 x (mu~0: no cancellation risk) ----------------
__global__ void k_colstats_f32(const float* __restrict__ X, float* __restrict__ sum,
                               float* __restrict__ sq) {
  int t = threadIdx.x;
  float s = 0.f, q = 0.f;
  for (int r = blockIdx.x; r < NN; r += gridDim.x) {
    float v = X[(size_t)r * 256 + t];
    s += v; q += v * v;
  }
  atomicAdd(&sum[t], s);
  atomicAdd(&sq[t], q);
}

// ---------------- BN apply to fp32 x -> bf16 xn ----------------
__global__ void k_bnx(const float* __restrict__ X, const float* __restrict__ sum,
                      const float* __restrict__ sq, const float* __restrict__ g,
                      const float* __restrict__ b, u16* __restrict__ Y) {
  int t = threadIdx.x;
  float mu = sum[t] * (1.0f / NN);
  float var = fmaxf(sq[t] * (1.0f / NN) - mu * mu, 0.f);
  float rs = rsqrtf(var + 1e-5f);
  float ga = g[t] * rs;
  float be = b[t] - mu * ga;
  for (int r = blockIdx.x; r < NN; r += gridDim.x) {
    float v = X[(size_t)r * 256 + t];
    Y[(size_t)r * 256 + t] = f2b(v * ga + be);
  }
}

// ---------------- BN + relu + residual: h = relu(bn(m2)) + h ----------------
__global__ void k_bnres(const u16* __restrict__ M2, const float* __restrict__ sum,
                        const float* __restrict__ sq, const float* __restrict__ g,
                        const float* __restrict__ b, u16* __restrict__ h) {
  int t = threadIdx.x;
  float mu = sum[t] * (1.0f / NN);
  float var = fmaxf(sq[t] * (1.0f / NN) - mu * mu, 0.f);
  float rs = rsqrtf(var + 1e-5f);
  float ga = g[t] * rs;
  float be = b[t] - mu * ga;
  for (int r = blockIdx.x; r < NN; r += gridDim.x) {
    float v = b2f(M2[(size_t)r * 256 + t]) * ga + be;
    v = fmaxf(v, 0.f);
    float hp = b2f(h[(size_t)r * 256 + t]);
    h[(size_t)r * 256 + t] = f2b(v + hp);
  }
}

// ---------------- aggregation: out[n] = h[n] + sum_{s in N(n)} h[s] ----------------
// 16/8/4/1 unroll ladder: up to 16 independent 512B row gathers in flight per wave
__global__ void k_agg(const u16* __restrict__ h, const int* __restrict__ indptr,
                      const int* __restrict__ cnt, const int* __restrict__ csr,
                      u16* __restrict__ out) {
  int w = threadIdx.x >> 6, l = threadIdx.x & 63;
  int node = blockIdx.x * 4 + w;
  if (node >= NN) return;
  int beg = indptr[node], deg = cnt[node];
  const ushort4* hv = (const ushort4*)h + l;   // row r at hv[r*64]
  ushort4 v = hv[(size_t)node * 64];
  float a0 = b2f(v.x), a1 = b2f(v.y), a2 = b2f(v.z), a3 = b2f(v.w);
  int i = 0;
  for (; i + 16 <= deg; i += 16) {
    int idx[16];
#pragma unroll
    for (int j = 0; j < 16; ++j) idx[j] = csr[beg + i + j];
    ushort4 u[16];
#pragma unroll
    for (int j = 0; j < 16; ++j) u[j] = hv[(size_t)idx[j] * 64];
#pragma unroll
    for (int j = 0; j < 16; ++j) {
      a0 += b2f(u[j].x); a1 += b2f(u[j].y); a2 += b2f(u[j].z); a3 += b2f(u[j].w);
    }
  }
  for (; i + 8 <= deg; i += 8) {
    int idx[8];
#pragma unroll
    for (int j = 0; j < 8; ++j) idx[j] = csr[beg + i + j];
    ushort4 u[8];
#pragma unroll
    for (int j = 0; j < 8; ++j) u[j] = hv[(size_t)idx[j] * 64];
#pragma unroll
    for (int j = 0; j < 8; ++j) {
      a0 += b2f(u[j].x); a1 += b2f(u[j].y); a2 += b2f(u[j].z); a3 += b2f(u[j].w);
    }
  }
  for (; i + 4 <= deg; i += 4) {
    int idx[4];
#pragma unroll
    for (int j = 0; j < 4; ++j) idx[j] = csr[beg + i + j];
    ushort4 u[4];
#pragma unroll
    for (int j = 0; j < 4; ++j) u[j] = hv[(size_t)idx[j] * 64];
#pragma unroll
    for (int j = 0; j < 4; ++j) {
      a0 += b2f(u[j].x); a1 += b2f(u[j].y); a2 += b2f(u[j].z); a3 += b2f(u[j].w);
    }
  }
  for (; i < deg; ++i) {
    int s = csr[beg + i];
    ushort4 u = hv[(size_t)s * 64];
    a0 += b2f(u.x); a1 += b2f(u.y); a2 += b2f(u.z); a3 += b2f(u.w);
  }
  ushort4 o;
  o.x = f2b(a0); o.y = f2b(a1); o.z = f2b(a2); o.w = f2b(a3);
  *((ushort4*)out + (size_t)node * 64 + l) = o;
}

// ---------------- GEMM: C = act(A @ W + bias); optional fused column stats ----------------
__global__ __launch_bounds__(256) void k_gemm(const u16* __restrict__ A,
                                              const u16* __restrict__ BT,
                                              const float* __restrict__ bias,
                                              u16* __restrict__ C, int relu,
                                              float* __restrict__ csum,
                                              float* __restrict__ csq, int dostats) {
  __shared__ __align__(16) u16 As[128 * LDSW];
  __shared__ __align__(16) u16 Bs[128 * LDSW];
  int tid = threadIdx.x;
  int bid = blockIdx.x;
  int tn = bid & 1, tm = bid >> 1;
  int w = tid >> 6, l = tid & 63;
  int wr = (w >> 1) * 64, wc = (w & 1) * 64;

  const u16* Ag = A + (size_t)tm * 128 * 256;
  const u16* Bg = BT + (size_t)tn * 128 * 256;

  f32x4 zz; zz[0] = 0.f; zz[1] = 0.f; zz[2] = 0.f; zz[3] = 0.f;
  f32x4 acc[4][4];
#pragma unroll
  for (int m = 0; m < 4; ++m)
#pragma unroll
    for (int n = 0; n < 4; ++n) acc[m][n] = zz;

  int r0 = w * 16 + (l >> 2);
  int r1 = r0 + 64;
  int kc = (l & 3) * 8;
  int w0 = r0 * LDSW + (l & 3) * 8;
  int w1 = r1 * LDSW + (l & 3) * 8;

  short8 pa0 = *(const short8*)(Ag + (size_t)r0 * 256 + kc);
  short8 pa1 = *(const short8*)(Ag + (size_t)r1 * 256 + kc);
  short8 pb0 = *(const short8*)(Bg + (size_t)r0 * 256 + kc);
  short8 pb1 = *(const short8*)(Bg + (size_t)r1 * 256 + kc);

  for (int kk = 0; kk < 8; ++kk) {
    *(short8*)&As[w0] = pa0;
    *(short8*)&As[w1] = pa1;
    *(short8*)&Bs[w0] = pb0;
    *(short8*)&Bs[w1] = pb1;
    if (kk < 7) {
      int k0 = (kk + 1) * 32 + kc;
      pa0 = *(const short8*)(Ag + (size_t)r0 * 256 + k0);
      pa1 = *(const short8*)(Ag + (size_t)r1 * 256 + k0);
      pb0 = *(const short8*)(Bg + (size_t)r0 * 256 + k0);
      pb1 = *(const short8*)(Bg + (size_t)r1 * 256 + k0);
    }
    __syncthreads();
    short8 af[4], bfr[4];
#pragma unroll
    for (int m = 0; m < 4; ++m) {
      int row = wr + m * 16 + (l & 15);
      af[m] = *(const short8*)&As[row * LDSW + (l >> 4) * 8];
    }
#pragma unroll
    for (int n = 0; n < 4; ++n) {
      int row = wc + n * 16 + (l & 15);
      bfr[n] = *(const short8*)&Bs[row * LDSW + (l >> 4) * 8];
    }
#pragma unroll
    for (int m = 0; m < 4; ++m)
#pragma unroll
      for (int n = 0; n < 4; ++n)
        acc[m][n] = __builtin_amdgcn_mfma_f32_16x16x32_bf16(af[m], bfr[n], acc[m][n], 0, 0, 0);
    __syncthreads();
  }

  int colb = tn * 128 + wc;
  int rowb = tm * 128 + wr + (l >> 4) * 4;
#pragma unroll
  for (int n = 0; n < 4; ++n) {
    int c = colb + n * 16 + (l & 15);
    float bz = bias[c];
    float s = 0.f, q = 0.f;
#pragma unroll
    for (int m = 0; m < 4; ++m) {
      int r = rowb + m * 16;
#pragma unroll
      for (int i = 0; i < 4; ++i) {
        float v = acc[m][n][i] + bz;
        if (relu) v = fmaxf(v, 0.f);
        C[(size_t)(r + i) * 256 + c] = f2b(v);
        if (dostats && (r + i) < NN) { s += v; q += v * v; }
      }
    }
    if (dostats) {
      s += __shfl_xor(s, 16); s += __shfl_xor(s, 32);
      q += __shfl_xor(q, 16); q += __shfl_xor(q, 32);
      if ((l >> 4) == 0) {
        atomicAdd(&csum[c], s);
        atomicAdd(&csq[c], q);
      }
    }
  }
}

// ---------------- pooling (batch sorted) ----------------
__global__ void k_pool(const u16* __restrict__ h, const int* __restrict__ batch,
                       float* __restrict__ pooled, int* __restrict__ gcnt) {
  __shared__ int bg[128];
  int t = threadIdx.x;
  int r0 = blockIdx.x * 128;
  int rend = min(r0 + 128, NN);
  if (r0 >= NN) return;
  if (t < 128 && r0 + t < NN) bg[t] = batch[r0 + t];
  __syncthreads();
  float a = 0.f;
  int cur = bg[0];
  int cl = 0;
  for (int r = r0; r < rend; ++r) {
    int g = bg[r - r0];
    if (g != cur) {
      atomicAdd(&pooled[(size_t)cur * 256 + t], a);
      if (t == 0) atomicAdd(&gcnt[cur], cl);
      a = 0.f; cl = 0; cur = g;
    }
    a += b2f(h[(size_t)r * 256 + t]);
    cl++;
  }
  atomicAdd(&pooled[(size_t)cur * 256 + t], a);
  if (t == 0) atomicAdd(&gcnt[cur], cl);
}

// ---------------- head: embed + logits (fp32 out) ----------------
__global__ void k_head(const float* __restrict__ pooled, const int* __restrict__ gcnt,
                       const float* __restrict__ predW, const float* __restrict__ predb,
                       float* __restrict__ out) {
  __shared__ float pm[256];
  int g = blockIdx.x, t = threadIdx.x;
  float c = fmaxf((float)gcnt[g], 1.0f);
  float v = pooled[(size_t)g * 256 + t] / c;
  pm[t] = v;
  out[(size_t)g * 256 + t] = v;
  __syncthreads();
  if (t < NOTESD) {
    float acc = predb[t];
    for (int k = 0; k < 256; ++k)
      acc += pm[k] * predW[k * NOTESD + t];
    out[(size_t)GG * 256 + (size_t)g * NOTESD + t] = acc;
  }
}

extern "C" void kernel_launch(void* const* d_in, const int* in_sizes, int n_in,
                              void* d_out, int out_size, void* d_ws, size_t ws_size,
                              hipStream_t stream) {
  const float* x     = (const float*)d_in[0];
  const int*   ei    = (const int*)d_in[1];
  const int*   batch = (const int*)d_in[2];
  const float* fng   = (const float*)d_in[3];
  const float* fnb   = (const float*)d_in[4];
  const float* projW = (const float*)d_in[5];
  const float* projb = (const float*)d_in[6];
  const float* W1    = (const float*)d_in[7];
  const float* b1    = (const float*)d_in[8];
  const float* W2    = (const float*)d_in[9];
  const float* b2    = (const float*)d_in[10];
  const float* bng   = (const float*)d_in[11];
  const float* bnb   = (const float*)d_in[12];
  const float* predW = (const float*)d_in[13];
  const float* predb = (const float*)d_in[14];
  float* out = (float*)d_out;

  char* ws = (char*)d_ws;
  size_t off = 0;
  auto alloc = [&](size_t b) { size_t o = off; off += (b + 255) & ~(size_t)255; return o; };
  u16* h    = (u16*)(ws + alloc((size_t)MPAD * 256 * 2));
  u16* bufA = (u16*)(ws + alloc((size_t)MPAD * 256 * 2));
  u16* bufB = (u16*)(ws + alloc((size_t)MPAD * 256 * 2));
  u16* wt   = (u16*)(ws + alloc((size_t)9 * 65536 * 2));
  int* cnt    = (int*)(ws + alloc((size_t)NN * 4));
  int* indptr = (int*)(ws + alloc((size_t)NN * 4));
  int* cursor = (int*)(ws + alloc((size_t)NN * 4));
  int* csum   = (int*)(ws + alloc(512));
  int* coff   = (int*)(ws + alloc(512));
  int* csr    = (int*)(ws + alloc((size_t)EE * 4));
  // contiguous stat zone: xsum/xsq | 4x(lsum/lsq) | pooled | gcnt  (one memset)
  size_t statbytes = (size_t)(2560 + GG * 256) * 4 + GG * 4;
  float* statz = (float*)(ws + alloc(statbytes));
  float* xsum = statz;
  float* xsq  = statz + 256;
  float* pooled = statz + 2560;
  int* gcnt = (int*)(statz + 2560 + GG * 256);

  const int* srcI = ei;
  const int* dstI = ei + EE;

  // CSR build
  hipMemsetAsync(cnt, 0, (size_t)NN * 4, stream);
  k_hist<<<(EE + 255) / 256, 256, 0, stream>>>(dstI, cnt);
  k_scan1<<<NCHUNK, 512, 0, stream>>>(cnt, indptr, csum);
  k_scan2<<<1, 128, 0, stream>>>(csum, coff);
  k_scan3<<<NCHUNK, 512, 0, stream>>>(coff, indptr, cursor);
  k_fill<<<(EE + 255) / 256, 256, 0, stream>>>(srcI, dstI, cursor, csr);

  // all weight transposes in one launch
  k_transpose_all<<<576, 256, 0, stream>>>(projW, W1, W2, wt);

  // zero all accumulators once + bufA pad rows
  hipMemsetAsync(statz, 0, statbytes, stream);
  hipMemsetAsync(bufA + (size_t)NN * 256, 0, (size_t)(MPAD - NN) * 256 * 2, stream);

  // feature BN -> bufA
  k_colstats_f32<<<512, 256, 0, stream>>>(x, xsum, xsq);
  k_bnx<<<512, 256, 0, stream>>>(x, xsum, xsq, fng, fnb, bufA);

  // projection: h = relu(xn @ projW + projb)
  k_gemm<<<TM_TILES * 2, 256, 0, stream>>>(bufA, wt, projb, h, 1, nullptr, nullptr, 0);

  for (int l = 0; l < 4; ++l) {
    float* lsum = statz + 512 + l * 512;
    float* lsq  = lsum + 256;
    k_agg<<<(NN + 3) / 4, 256, 0, stream>>>(h, indptr, cnt, csr, bufA);
    k_gemm<<<TM_TILES * 2, 256, 0, stream>>>(bufA, wt + (size_t)(1 + l) * 65536,
                                             b1 + (size_t)l * 256, bufB, 1, nullptr, nullptr, 0);
    k_gemm<<<TM_TILES * 2, 256, 0, stream>>>(bufB, wt + (size_t)(5 + l) * 65536,
                                             b2 + (size_t)l * 256, bufA, 0, lsum, lsq, 1);
    k_bnres<<<512, 256, 0, stream>>>(bufA, lsum, lsq, bng + (size_t)l * 256,
                                     bnb + (size_t)l * 256, h);
  }

  // readout
  k_pool<<<(NN + 127) / 128, 256, 0, stream>>>(h, batch, pooled, gcnt);
  k_head<<<GG, 256, 0, stream>>>(pooled, gcnt, predW, predb, out);
}

// Round 11
// 757.185 us; speedup vs baseline: 1.5553x; 1.0667x over previous
//
#include <hip/hip_runtime.h>
#include <hip/hip_bf16.h>
#include <stdint.h>

#define NN 50000
#define EE 800000
#define GG 64
#define NOTESD 128
#define MPAD 50048
#define TM_TILES 391
#define NCHUNK 98
#define LDSW 40

typedef unsigned short u16;
typedef __attribute__((ext_vector_type(8))) short short8;
typedef __attribute__((ext_vector_type(4))) float f32x4;

__device__ __forceinline__ float b2f(u16 u) {
  union { uint32_t i; float f; } x; x.i = ((uint32_t)u) << 16; return x.f;
}
__device__ __forceinline__ u16 f2b(float f) {
  __hip_bfloat16 h = __float2bfloat16(f);
  return *reinterpret_cast<u16*>(&h);
}

// ---------------- CSR build ----------------
__global__ void k_hist(const int* __restrict__ dst, int* __restrict__ cnt) {
  int e = blockIdx.x * 256 + threadIdx.x;
  if (e < EE) atomicAdd(&cnt[dst[e]], 1);
}

__global__ void k_scan1(const int* __restrict__ cnt, int* __restrict__ indptr,
                        int* __restrict__ csum) {
  __shared__ int s[512];
  int t = threadIdx.x;
  int i = blockIdx.x * 512 + t;
  int v = (i < NN) ? cnt[i] : 0;
  s[t] = v; __syncthreads();
  for (int d = 1; d < 512; d <<= 1) {
    int x = (t >= d) ? s[t - d] : 0;
    __syncthreads();
    s[t] += x;
    __syncthreads();
  }
  if (i < NN) indptr[i] = s[t] - v;
  if (t == 511) csum[blockIdx.x] = s[t];
}

__global__ void k_scan2(const int* __restrict__ csum, int* __restrict__ coff) {
  __shared__ int s[128];
  int t = threadIdx.x;
  int v = (t < NCHUNK) ? csum[t] : 0;
  s[t] = v; __syncthreads();
  for (int d = 1; d < 128; d <<= 1) {
    int x = (t >= d) ? s[t - d] : 0;
    __syncthreads();
    s[t] += x;
    __syncthreads();
  }
  if (t < NCHUNK) coff[t] = s[t] - v;
}

__global__ void k_scan3(const int* __restrict__ coff, int* __restrict__ indptr,
                        int* __restrict__ cursor) {
  int i = blockIdx.x * 512 + threadIdx.x;
  if (i < NN) {
    int v = indptr[i] + coff[blockIdx.x];
    indptr[i] = v;
    cursor[i] = v;
  }
}

__global__ void k_fill(const int* __restrict__ src, const int* __restrict__ dst,
                       int* __restrict__ cursor, int* __restrict__ csr) {
  int e = blockIdx.x * 256 + threadIdx.x;
  if (e < EE) {
    int p = atomicAdd(&cursor[dst[e]], 1);
    csr[p] = src[e];
  }
}

// ---------------- all 9 weight transposes (fp32 -> bf16, 256x256 each) ----------------
__global__ void k_transpose_all(const float* __restrict__ proj, const float* __restrict__ W1,
                                const float* __restrict__ W2, u16* __restrict__ WT) {
  __shared__ float tile[32][33];
  int mat = blockIdx.x >> 6;
  int bid = blockIdx.x & 63;
  const float* W = (mat == 0) ? proj
                 : (mat <= 4) ? W1 + (size_t)(mat - 1) * 65536
                              : W2 + (size_t)(mat - 5) * 65536;
  u16* dst = WT + (size_t)mat * 65536;
  int bx = bid & 7, by = bid >> 3;
  int tx = threadIdx.x & 31, ty = threadIdx.x >> 5;
#pragma unroll
  for (int i = 0; i < 32; i += 8)
    tile[ty + i][tx] = W[(by * 32 + ty + i) * 256 + bx * 32 + tx];
  __syncthreads();
#pragma unroll
  for (int i = 0; i < 32; i += 8)
    dst[(bx * 32 + ty + i) * 256 + by * 32 + tx] = f2b(tile[tx][ty + i]);
}

// ---------------- one-pass column stats for fp32 x (mu~0: no cancellation risk) ----------------
__global__ void k_colstats_f32(const float* __restrict__ X, float* __restrict__ sum,
                               float* __restrict__ sq) {
  int t = threadIdx.x;
  float s = 0.f, q = 0.f;
  for (int r = blockIdx.x; r < NN; r += gridDim.x) {
    float v = X[(size_t)r * 256 + t];
    s += v; q += v * v;
  }
  atomicAdd(&sum[t], s);
  atomicAdd(&sq[t], q);
}

// ---------------- BN apply to fp32 x -> bf16 xn ----------------
__global__ void k_bnx(const float* __restrict__ X, const float* __restrict__ sum,
                      const float* __restrict__ sq, const float* __restrict__ g,
                      const float* __restrict__ b, u16* __restrict__ Y) {
  int t = threadIdx.x;
  float mu = sum[t] * (1.0f / NN);
  float var = fmaxf(sq[t] * (1.0f / NN) - mu * mu, 0.f);
  float rs = rsqrtf(var + 1e-5f);
  float ga = g[t] * rs;
  float be = b[t] - mu * ga;
  for (int r = blockIdx.x; r < NN; r += gridDim.x) {
    float v = X[(size_t)r * 256 + t];
    Y[(size_t)r * 256 + t] = f2b(v * ga + be);
  }
}

// ---------------- BN + relu + residual: h = relu(bn(m2)) + h ----------------
__global__ void k_bnres(const u16* __restrict__ M2, const float* __restrict__ sum,
                        const float* __restrict__ sq, const float* __restrict__ g,
                        const float* __restrict__ b, u16* __restrict__ h) {
  int t = threadIdx.x;
  float mu = sum[t] * (1.0f / NN);
  float var = fmaxf(sq[t] * (1.0f / NN) - mu * mu, 0.f);
  float rs = rsqrtf(var + 1e-5f);
  float ga = g[t] * rs;
  float be = b[t] - mu * ga;
  for (int r = blockIdx.x; r < NN; r += gridDim.x) {
    float v = b2f(M2[(size_t)r * 256 + t]) * ga + be;
    v = fmaxf(v, 0.f);
    float hp = b2f(h[(size_t)r * 256 + t]);
    h[(size_t)r * 256 + t] = f2b(v + hp);
  }
}

// ---------------- aggregation: 8/4/1 ladder (R9 version: 57.2us, 66% occ) ----------------
__global__ void k_agg(const u16* __restrict__ h, const int* __restrict__ indptr,
                      const int* __restrict__ cnt, const int* __restrict__ csr,
                      u16* __restrict__ out) {
  int w = threadIdx.x >> 6, l = threadIdx.x & 63;
  int node = blockIdx.x * 4 + w;
  if (node >= NN) return;
  int beg = indptr[node], deg = cnt[node];
  const ushort4* hv = (const ushort4*)h + l;
  ushort4 v = hv[(size_t)node * 64];
  float a0 = b2f(v.x), a1 = b2f(v.y), a2 = b2f(v.z), a3 = b2f(v.w);
  int i = 0;
  for (; i + 8 <= deg; i += 8) {
    int s0 = csr[beg + i + 0], s1 = csr[beg + i + 1];
    int s2 = csr[beg + i + 2], s3 = csr[beg + i + 3];
    int s4 = csr[beg + i + 4], s5 = csr[beg + i + 5];
    int s6 = csr[beg + i + 6], s7 = csr[beg + i + 7];
    ushort4 u0 = hv[(size_t)s0 * 64], u1 = hv[(size_t)s1 * 64];
    ushort4 u2 = hv[(size_t)s2 * 64], u3 = hv[(size_t)s3 * 64];
    ushort4 u4 = hv[(size_t)s4 * 64], u5 = hv[(size_t)s5 * 64];
    ushort4 u6 = hv[(size_t)s6 * 64], u7 = hv[(size_t)s7 * 64];
    a0 += b2f(u0.x) + b2f(u1.x) + b2f(u2.x) + b2f(u3.x)
        + b2f(u4.x) + b2f(u5.x) + b2f(u6.x) + b2f(u7.x);
    a1 += b2f(u0.y) + b2f(u1.y) + b2f(u2.y) + b2f(u3.y)
        + b2f(u4.y) + b2f(u5.y) + b2f(u6.y) + b2f(u7.y);
    a2 += b2f(u0.z) + b2f(u1.z) + b2f(u2.z) + b2f(u3.z)
        + b2f(u4.z) + b2f(u5.z) + b2f(u6.z) + b2f(u7.z);
    a3 += b2f(u0.w) + b2f(u1.w) + b2f(u2.w) + b2f(u3.w)
        + b2f(u4.w) + b2f(u5.w) + b2f(u6.w) + b2f(u7.w);
  }
  for (; i + 4 <= deg; i += 4) {
    int s0 = csr[beg + i + 0], s1 = csr[beg + i + 1];
    int s2 = csr[beg + i + 2], s3 = csr[beg + i + 3];
    ushort4 u0 = hv[(size_t)s0 * 64], u1 = hv[(size_t)s1 * 64];
    ushort4 u2 = hv[(size_t)s2 * 64], u3 = hv[(size_t)s3 * 64];
    a0 += b2f(u0.x) + b2f(u1.x) + b2f(u2.x) + b2f(u3.x);
    a1 += b2f(u0.y) + b2f(u1.y) + b2f(u2.y) + b2f(u3.y);
    a2 += b2f(u0.z) + b2f(u1.z) + b2f(u2.z) + b2f(u3.z);
    a3 += b2f(u0.w) + b2f(u1.w) + b2f(u2.w) + b2f(u3.w);
  }
  for (; i < deg; ++i) {
    int s = csr[beg + i];
    ushort4 u = hv[(size_t)s * 64];
    a0 += b2f(u.x); a1 += b2f(u.y); a2 += b2f(u.z); a3 += b2f(u.w);
  }
  ushort4 o;
  o.x = f2b(a0); o.y = f2b(a1); o.z = f2b(a2); o.w = f2b(a3);
  *((ushort4*)out + (size_t)node * 64 + l) = o;
}

// ---------------- GEMM (proj only): C = relu(A @ W + bias) ----------------
__global__ __launch_bounds__(256) void k_gemm(const u16* __restrict__ A,
                                              const u16* __restrict__ BT,
                                              const float* __restrict__ bias,
                                              u16* __restrict__ C, int relu) {
  __shared__ __align__(16) u16 As[128 * LDSW];
  __shared__ __align__(16) u16 Bs[128 * LDSW];
  int tid = threadIdx.x;
  int bid = blockIdx.x;
  int tn = bid & 1, tm = bid >> 1;
  int w = tid >> 6, l = tid & 63;
  int wr = (w >> 1) * 64, wc = (w & 1) * 64;

  const u16* Ag = A + (size_t)tm * 128 * 256;
  const u16* Bg = BT + (size_t)tn * 128 * 256;

  f32x4 zz; zz[0] = 0.f; zz[1] = 0.f; zz[2] = 0.f; zz[3] = 0.f;
  f32x4 acc[4][4];
#pragma unroll
  for (int m = 0; m < 4; ++m)
#pragma unroll
    for (int n = 0; n < 4; ++n) acc[m][n] = zz;

  int r0 = w * 16 + (l >> 2);
  int r1 = r0 + 64;
  int kc = (l & 3) * 8;
  int w0 = r0 * LDSW + (l & 3) * 8;
  int w1 = r1 * LDSW + (l & 3) * 8;

  short8 pa0 = *(const short8*)(Ag + (size_t)r0 * 256 + kc);
  short8 pa1 = *(const short8*)(Ag + (size_t)r1 * 256 + kc);
  short8 pb0 = *(const short8*)(Bg + (size_t)r0 * 256 + kc);
  short8 pb1 = *(const short8*)(Bg + (size_t)r1 * 256 + kc);

  for (int kk = 0; kk < 8; ++kk) {
    *(short8*)&As[w0] = pa0;
    *(short8*)&As[w1] = pa1;
    *(short8*)&Bs[w0] = pb0;
    *(short8*)&Bs[w1] = pb1;
    if (kk < 7) {
      int k0 = (kk + 1) * 32 + kc;
      pa0 = *(const short8*)(Ag + (size_t)r0 * 256 + k0);
      pa1 = *(const short8*)(Ag + (size_t)r1 * 256 + k0);
      pb0 = *(const short8*)(Bg + (size_t)r0 * 256 + k0);
      pb1 = *(const short8*)(Bg + (size_t)r1 * 256 + k0);
    }
    __syncthreads();
    short8 af[4], bfr[4];
#pragma unroll
    for (int m = 0; m < 4; ++m) {
      int row = wr + m * 16 + (l & 15);
      af[m] = *(const short8*)&As[row * LDSW + (l >> 4) * 8];
    }
#pragma unroll
    for (int n = 0; n < 4; ++n) {
      int row = wc + n * 16 + (l & 15);
      bfr[n] = *(const short8*)&Bs[row * LDSW + (l >> 4) * 8];
    }
#pragma unroll
    for (int m = 0; m < 4; ++m)
#pragma unroll
      for (int n = 0; n < 4; ++n)
        acc[m][n] = __builtin_amdgcn_mfma_f32_16x16x32_bf16(af[m], bfr[n], acc[m][n], 0, 0, 0);
    __syncthreads();
  }

  int colb = tn * 128 + wc;
  int rowb = tm * 128 + wr + (l >> 4) * 4;
#pragma unroll
  for (int n = 0; n < 4; ++n) {
    int c = colb + n * 16 + (l & 15);
    float bz = bias[c];
#pragma unroll
    for (int m = 0; m < 4; ++m) {
      int r = rowb + m * 16;
#pragma unroll
      for (int i = 0; i < 4; ++i) {
        float v = acc[m][n][i] + bz;
        if (relu) v = fmaxf(v, 0.f);
        C[(size_t)(r + i) * 256 + c] = f2b(v);
      }
    }
  }
}

// ---------------- fused GIN MLP: C = relu(A@W1+b1)@W2+b2, stats fused ----------------
// block: 64 rows x 256 cols; 4 waves each 64r x 64c; C1 kept bf16 in LDS (chunk-major)
__global__ __launch_bounds__(256) void k_mlp(const u16* __restrict__ A,
                                             const u16* __restrict__ B1T,
                                             const u16* __restrict__ B2T,
                                             const float* __restrict__ b1,
                                             const float* __restrict__ b2,
                                             u16* __restrict__ C,
                                             float* __restrict__ csum,
                                             float* __restrict__ csq) {
  __shared__ __align__(16) u16 As[64 * LDSW];
  __shared__ __align__(16) u16 Bs[256 * LDSW];
  __shared__ __align__(16) u16 C1[8 * 64 * LDSW];  // [chunk][row][k&31]
  int tid = threadIdx.x;
  int tm = blockIdx.x;
  int w = tid >> 6, l = tid & 63;
  int wc = w * 64;

  const u16* Ag = A + (size_t)tm * 64 * 256;

  int sr = tid >> 2;            // 0..63
  int skc = (tid & 3) * 8;      // k offset in chunk
  int aw = sr * LDSW + skc;

  f32x4 zz; zz[0] = 0.f; zz[1] = 0.f; zz[2] = 0.f; zz[3] = 0.f;
  f32x4 acc[4][4];
#pragma unroll
  for (int m = 0; m < 4; ++m)
#pragma unroll
    for (int n = 0; n < 4; ++n) acc[m][n] = zz;

  // ---- phase 1: C1 = relu(A @ W1 + b1) ----
  short8 pa = *(const short8*)(Ag + (size_t)sr * 256 + skc);
  short8 pb[4];
#pragma unroll
  for (int j = 0; j < 4; ++j)
    pb[j] = *(const short8*)(B1T + (size_t)(sr + 64 * j) * 256 + skc);

  for (int kk = 0; kk < 8; ++kk) {
    *(short8*)&As[aw] = pa;
#pragma unroll
    for (int j = 0; j < 4; ++j)
      *(short8*)&Bs[(sr + 64 * j) * LDSW + skc] = pb[j];
    if (kk < 7) {
      int k0 = (kk + 1) * 32 + skc;
      pa = *(const short8*)(Ag + (size_t)sr * 256 + k0);
#pragma unroll
      for (int j = 0; j < 4; ++j)
        pb[j] = *(const short8*)(B1T + (size_t)(sr + 64 * j) * 256 + k0);
    }
    __syncthreads();
    short8 af[4], bfr[4];
#pragma unroll
    for (int m = 0; m < 4; ++m)
      af[m] = *(const short8*)&As[(m * 16 + (l & 15)) * LDSW + (l >> 4) * 8];
#pragma unroll
    for (int n = 0; n < 4; ++n)
      bfr[n] = *(const short8*)&Bs[(wc + n * 16 + (l & 15)) * LDSW + (l >> 4) * 8];
#pragma unroll
    for (int m = 0; m < 4; ++m)
#pragma unroll
      for (int n = 0; n < 4; ++n)
        acc[m][n] = __builtin_amdgcn_mfma_f32_16x16x32_bf16(af[m], bfr[n], acc[m][n], 0, 0, 0);
    __syncthreads();
  }

  // prefetch W2 chunk 0 (hide latency under epilogue 1)
  short8 qb[4];
#pragma unroll
  for (int j = 0; j < 4; ++j)
    qb[j] = *(const short8*)(B2T + (size_t)(sr + 64 * j) * 256 + skc);

  // epilogue 1 -> C1 (LDS, chunk-major), add b1, relu
  {
    int rbase = (l >> 4) * 4;
#pragma unroll
    for (int n = 0; n < 4; ++n) {
      int c = wc + n * 16 + (l & 15);
      float bz = b1[c];
      u16* c1p = &C1[(c >> 5) * (64 * LDSW) + (c & 31)];
#pragma unroll
      for (int m = 0; m < 4; ++m) {
#pragma unroll
        for (int i = 0; i < 4; ++i) {
          float v = fmaxf(acc[m][n][i] + bz, 0.f);
          c1p[(m * 16 + rbase + i) * LDSW] = f2b(v);
        }
        acc[m][n] = zz;  // re-zero for phase 2
      }
    }
  }

  // ---- phase 2: C = C1 @ W2 + b2 ----
  for (int kk = 0; kk < 8; ++kk) {
#pragma unroll
    for (int j = 0; j < 4; ++j)
      *(short8*)&Bs[(sr + 64 * j) * LDSW + skc] = qb[j];
    if (kk < 7) {
      int k0 = (kk + 1) * 32 + skc;
#pragma unroll
      for (int j = 0; j < 4; ++j)
        qb[j] = *(const short8*)(B2T + (size_t)(sr + 64 * j) * 256 + k0);
    }
    __syncthreads();  // C1 writes (kk=0) + Bs chunk visible
    short8 af[4], bfr[4];
#pragma unroll
    for (int m = 0; m < 4; ++m)
      af[m] = *(const short8*)&C1[kk * (64 * LDSW) + (m * 16 + (l & 15)) * LDSW + (l >> 4) * 8];
#pragma unroll
    for (int n = 0; n < 4; ++n)
      bfr[n] = *(const short8*)&Bs[(wc + n * 16 + (l & 15)) * LDSW + (l >> 4) * 8];
#pragma unroll
    for (int m = 0; m < 4; ++m)
#pragma unroll
      for (int n = 0; n < 4; ++n)
        acc[m][n] = __builtin_amdgcn_mfma_f32_16x16x32_bf16(af[m], bfr[n], acc[m][n], 0, 0, 0);
    __syncthreads();
  }

  // epilogue 2 -> global + fused stats
  int rowb = tm * 64 + (l >> 4) * 4;
#pragma unroll
  for (int n = 0; n < 4; ++n) {
    int c = wc + n * 16 + (l & 15);
    float bz = b2[c];
    float s = 0.f, q = 0.f;
#pragma unroll
    for (int m = 0; m < 4; ++m) {
      int r = rowb + m * 16;
#pragma unroll
      for (int i = 0; i < 4; ++i) {
        float v = acc[m][n][i] + bz;
        C[(size_t)(r + i) * 256 + c] = f2b(v);
        if ((r + i) < NN) { s += v; q += v * v; }
      }
    }
    s += __shfl_xor(s, 16); s += __shfl_xor(s, 32);
    q += __shfl_xor(q, 16); q += __shfl_xor(q, 32);
    if ((l >> 4) == 0) {
      atomicAdd(&csum[c], s);
      atomicAdd(&csq[c], q);
    }
  }
}

// ---------------- pooling (batch sorted) ----------------
__global__ void k_pool(const u16* __restrict__ h, const int* __restrict__ batch,
                       float* __restrict__ pooled, int* __restrict__ gcnt) {
  __shared__ int bg[128];
  int t = threadIdx.x;
  int r0 = blockIdx.x * 128;
  int rend = min(r0 + 128, NN);
  if (r0 >= NN) return;
  if (t < 128 && r0 + t < NN) bg[t] = batch[r0 + t];
  __syncthreads();
  float a = 0.f;
  int cur = bg[0];
  int cl = 0;
  for (int r = r0; r < rend; ++r) {
    int g = bg[r - r0];
    if (g != cur) {
      atomicAdd(&pooled[(size_t)cur * 256 + t], a);
      if (t == 0) atomicAdd(&gcnt[cur], cl);
      a = 0.f; cl = 0; cur = g;
    }
    a += b2f(h[(size_t)r * 256 + t]);
    cl++;
  }
  atomicAdd(&pooled[(size_t)cur * 256 + t], a);
  if (t == 0) atomicAdd(&gcnt[cur], cl);
}

// ---------------- head: embed + logits (fp32 out) ----------------
__global__ void k_head(const float* __restrict__ pooled, const int* __restrict__ gcnt,
                       const float* __restrict__ predW, const float* __restrict__ predb,
                       float* __restrict__ out) {
  __shared__ float pm[256];
  int g = blockIdx.x, t = threadIdx.x;
  float c = fmaxf((float)gcnt[g], 1.0f);
  float v = pooled[(size_t)g * 256 + t] / c;
  pm[t] = v;
  out[(size_t)g * 256 + t] = v;
  __syncthreads();
  if (t < NOTESD) {
    float acc = predb[t];
    for (int k = 0; k < 256; ++k)
      acc += pm[k] * predW[k * NOTESD + t];
    out[(size_t)GG * 256 + (size_t)g * NOTESD + t] = acc;
  }
}

extern "C" void kernel_launch(void* const* d_in, const int* in_sizes, int n_in,
                              void* d_out, int out_size, void* d_ws, size_t ws_size,
                              hipStream_t stream) {
  const float* x     = (const float*)d_in[0];
  const int*   ei    = (const int*)d_in[1];
  const int*   batch = (const int*)d_in[2];
  const float* fng   = (const float*)d_in[3];
  const float* fnb   = (const float*)d_in[4];
  const float* projW = (const float*)d_in[5];
  const float* projb = (const float*)d_in[6];
  const float* W1    = (const float*)d_in[7];
  const float* b1    = (const float*)d_in[8];
  const float* W2    = (const float*)d_in[9];
  const float* b2    = (const float*)d_in[10];
  const float* bng   = (const float*)d_in[11];
  const float* bnb   = (const float*)d_in[12];
  const float* predW = (const float*)d_in[13];
  const float* predb = (const float*)d_in[14];
  float* out = (float*)d_out;

  char* ws = (char*)d_ws;
  size_t off = 0;
  auto alloc = [&](size_t b) { size_t o = off; off += (b + 255) & ~(size_t)255; return o; };
  u16* h    = (u16*)(ws + alloc((size_t)MPAD * 256 * 2));
  u16* bufA = (u16*)(ws + alloc((size_t)MPAD * 256 * 2));
  u16* bufB = (u16*)(ws + alloc((size_t)MPAD * 256 * 2));
  u16* wt   = (u16*)(ws + alloc((size_t)9 * 65536 * 2));
  int* cnt    = (int*)(ws + alloc((size_t)NN * 4));
  int* indptr = (int*)(ws + alloc((size_t)NN * 4));
  int* cursor = (int*)(ws + alloc((size_t)NN * 4));
  int* csum   = (int*)(ws + alloc(512));
  int* coff   = (int*)(ws + alloc(512));
  int* csr    = (int*)(ws + alloc((size_t)EE * 4));
  size_t statbytes = (size_t)(2560 + GG * 256) * 4 + GG * 4;
  float* statz = (float*)(ws + alloc(statbytes));
  float* xsum = statz;
  float* xsq  = statz + 256;
  float* pooled = statz + 2560;
  int* gcnt = (int*)(statz + 2560 + GG * 256);

  const int* srcI = ei;
  const int* dstI = ei + EE;

  // CSR build
  hipMemsetAsync(cnt, 0, (size_t)NN * 4, stream);
  k_hist<<<(EE + 255) / 256, 256, 0, stream>>>(dstI, cnt);
  k_scan1<<<NCHUNK, 512, 0, stream>>>(cnt, indptr, csum);
  k_scan2<<<1, 128, 0, stream>>>(csum, coff);
  k_scan3<<<NCHUNK, 512, 0, stream>>>(coff, indptr, cursor);
  k_fill<<<(EE + 255) / 256, 256, 0, stream>>>(srcI, dstI, cursor, csr);

  // all weight transposes in one launch
  k_transpose_all<<<576, 256, 0, stream>>>(projW, W1, W2, wt);

  // zero accumulators + bufA pad rows (once)
  hipMemsetAsync(statz, 0, statbytes, stream);
  hipMemsetAsync(bufA + (size_t)NN * 256, 0, (size_t)(MPAD - NN) * 256 * 2, stream);

  // feature BN -> bufA
  k_colstats_f32<<<512, 256, 0, stream>>>(x, xsum, xsq);
  k_bnx<<<512, 256, 0, stream>>>(x, xsum, xsq, fng, fnb, bufA);

  // projection: h = relu(xn @ projW + projb)
  k_gemm<<<TM_TILES * 2, 256, 0, stream>>>(bufA, wt, projb, h, 1);

  for (int l = 0; l < 4; ++l) {
    float* lsum = statz + 512 + l * 512;
    float* lsq  = lsum + 256;
    k_agg<<<(NN + 3) / 4, 256, 0, stream>>>(h, indptr, cnt, csr, bufA);
    k_mlp<<<MPAD / 64, 256, 0, stream>>>(bufA, wt + (size_t)(1 + l) * 65536,
                                         wt + (size_t)(5 + l) * 65536,
                                         b1 + (size_t)l * 256, b2 + (size_t)l * 256,
                                         bufB, lsum, lsq);
    k_bnres<<<512, 256, 0, stream>>>(bufB, lsum, lsq, bng + (size_t)l * 256,
                                     bnb + (size_t)l * 256, h);
  }

  // readout
  k_pool<<<(NN + 127) / 128, 256, 0, stream>>>(h, batch, pooled, gcnt);
  k_head<<<GG, 256, 0, stream>>>(pooled, gcnt, predW, predb, out);
}

// Round 13
// 755.805 us; speedup vs baseline: 1.5581x; 1.0018x over previous
//
#include <hip/hip_runtime.h>
#include <hip/hip_bf16.h>
#include <stdint.h>

#define NN 50000
#define EE 800000
#define GG 64
#define NOTESD 128
#define MPAD 50048
#define TM_TILES 391
#define NCHUNK 98
#define LDSW 40

typedef unsigned short u16;
typedef __attribute__((ext_vector_type(8))) short short8;
typedef __attribute__((ext_vector_type(4))) float f32x4;

__device__ __forceinline__ float b2f(u16 u) {
  union { uint32_t i; float f; } x; x.i = ((uint32_t)u) << 16; return x.f;
}
__device__ __forceinline__ u16 f2b(float f) {
  __hip_bfloat16 h = __float2bfloat16(f);
  return *reinterpret_cast<u16*>(&h);
}

// ---------------- CSR build ----------------
__global__ void k_hist(const int* __restrict__ dst, int* __restrict__ cnt) {
  int e = blockIdx.x * 256 + threadIdx.x;
  if (e < EE) atomicAdd(&cnt[dst[e]], 1);
}

__global__ void k_scan1(const int* __restrict__ cnt, int* __restrict__ indptr,
                        int* __restrict__ csum) {
  __shared__ int s[512];
  int t = threadIdx.x;
  int i = blockIdx.x * 512 + t;
  int v = (i < NN) ? cnt[i] : 0;
  s[t] = v; __syncthreads();
  for (int d = 1; d < 512; d <<= 1) {
    int x = (t >= d) ? s[t - d] : 0;
    __syncthreads();
    s[t] += x;
    __syncthreads();
  }
  if (i < NN) indptr[i] = s[t] - v;
  if (t == 511) csum[blockIdx.x] = s[t];
}

__global__ void k_scan2(const int* __restrict__ csum, int* __restrict__ coff) {
  __shared__ int s[128];
  int t = threadIdx.x;
  int v = (t < NCHUNK) ? csum[t] : 0;
  s[t] = v; __syncthreads();
  for (int d = 1; d < 128; d <<= 1) {
    int x = (t >= d) ? s[t - d] : 0;
    __syncthreads();
    s[t] += x;
    __syncthreads();
  }
  if (t < NCHUNK) coff[t] = s[t] - v;
}

__global__ void k_scan3(const int* __restrict__ coff, int* __restrict__ indptr,
                        int* __restrict__ cursor) {
  int i = blockIdx.x * 512 + threadIdx.x;
  if (i < NN) {
    int v = indptr[i] + coff[blockIdx.x];
    indptr[i] = v;
    cursor[i] = v;
  }
}

__global__ void k_fill(const int* __restrict__ src, const int* __restrict__ dst,
                       int* __restrict__ cursor, int* __restrict__ csr) {
  int e = blockIdx.x * 256 + threadIdx.x;
  if (e < EE) {
    int p = atomicAdd(&cursor[dst[e]], 1);
    csr[p] = src[e];
  }
}

// ---------------- all 9 weight transposes (fp32 -> bf16, 256x256 each) ----------------
__global__ void k_transpose_all(const float* __restrict__ proj, const float* __restrict__ W1,
                                const float* __restrict__ W2, u16* __restrict__ WT) {
  __shared__ float tile[32][33];
  int mat = blockIdx.x >> 6;
  int bid = blockIdx.x & 63;
  const float* W = (mat == 0) ? proj
                 : (mat <= 4) ? W1 + (size_t)(mat - 1) * 65536
                              : W2 + (size_t)(mat - 5) * 65536;
  u16* dst = WT + (size_t)mat * 65536;
  int bx = bid & 7, by = bid >> 3;
  int tx = threadIdx.x & 31, ty = threadIdx.x >> 5;
#pragma unroll
  for (int i = 0; i < 32; i += 8)
    tile[ty + i][tx] = W[(by * 32 + ty + i) * 256 + bx * 32 + tx];
  __syncthreads();
#pragma unroll
  for (int i = 0; i < 32; i += 8)
    dst[(bx * 32 + ty + i) * 256 + by * 32 + tx] = f2b(tile[tx][ty + i]);
}

// ---------------- one-pass column stats for fp32 x ----------------
__global__ void k_colstats_f32(const float* __restrict__ X, float* __restrict__ sum,
                               float* __restrict__ sq) {
  int t = threadIdx.x;
  float s = 0.f, q = 0.f;
  for (int r = blockIdx.x; r < NN; r += gridDim.x) {
    float v = X[(size_t)r * 256 + t];
    s += v; q += v * v;
  }
  atomicAdd(&sum[t], s);
  atomicAdd(&sq[t], q);
}

// ---------------- BN apply to fp32 x -> bf16 xn ----------------
__global__ void k_bnx(const float* __restrict__ X, const float* __restrict__ sum,
                      const float* __restrict__ sq, const float* __restrict__ g,
                      const float* __restrict__ b, u16* __restrict__ Y) {
  int t = threadIdx.x;
  float mu = sum[t] * (1.0f / NN);
  float var = fmaxf(sq[t] * (1.0f / NN) - mu * mu, 0.f);
  float rs = rsqrtf(var + 1e-5f);
  float ga = g[t] * rs;
  float be = b[t] - mu * ga;
  for (int r = blockIdx.x; r < NN; r += gridDim.x) {
    float v = X[(size_t)r * 256 + t];
    Y[(size_t)r * 256 + t] = f2b(v * ga + be);
  }
}

// ---------------- BN + relu + residual: h = relu(bn(m2)) + h ----------------
__global__ void k_bnres(const u16* __restrict__ M2, const float* __restrict__ sum,
                        const float* __restrict__ sq, const float* __restrict__ g,
                        const float* __restrict__ b, u16* __restrict__ h) {
  int t = threadIdx.x;
  float mu = sum[t] * (1.0f / NN);
  float var = fmaxf(sq[t] * (1.0f / NN) - mu * mu, 0.f);
  float rs = rsqrtf(var + 1e-5f);
  float ga = g[t] * rs;
  float be = b[t] - mu * ga;
  for (int r = blockIdx.x; r < NN; r += gridDim.x) {
    float v = b2f(M2[(size_t)r * 256 + t]) * ga + be;
    v = fmaxf(v, 0.f);
    float hp = b2f(h[(size_t)r * 256 + t]);
    h[(size_t)r * 256 + t] = f2b(v + hp);
  }
}

// ---------------- aggregation: 8/4/1 ladder ----------------
__global__ void k_agg(const u16* __restrict__ h, const int* __restrict__ indptr,
                      const int* __restrict__ cnt, const int* __restrict__ csr,
                      u16* __restrict__ out) {
  int w = threadIdx.x >> 6, l = threadIdx.x & 63;
  int node = blockIdx.x * 4 + w;
  if (node >= NN) return;
  int beg = indptr[node], deg = cnt[node];
  const ushort4* hv = (const ushort4*)h + l;
  ushort4 v = hv[(size_t)node * 64];
  float a0 = b2f(v.x), a1 = b2f(v.y), a2 = b2f(v.z), a3 = b2f(v.w);
  int i = 0;
  for (; i + 8 <= deg; i += 8) {
    int s0 = csr[beg + i + 0], s1 = csr[beg + i + 1];
    int s2 = csr[beg + i + 2], s3 = csr[beg + i + 3];
    int s4 = csr[beg + i + 4], s5 = csr[beg + i + 5];
    int s6 = csr[beg + i + 6], s7 = csr[beg + i + 7];
    ushort4 u0 = hv[(size_t)s0 * 64], u1 = hv[(size_t)s1 * 64];
    ushort4 u2 = hv[(size_t)s2 * 64], u3 = hv[(size_t)s3 * 64];
    ushort4 u4 = hv[(size_t)s4 * 64], u5 = hv[(size_t)s5 * 64];
    ushort4 u6 = hv[(size_t)s6 * 64], u7 = hv[(size_t)s7 * 64];
    a0 += b2f(u0.x) + b2f(u1.x) + b2f(u2.x) + b2f(u3.x)
        + b2f(u4.x) + b2f(u5.x) + b2f(u6.x) + b2f(u7.x);
    a1 += b2f(u0.y) + b2f(u1.y) + b2f(u2.y) + b2f(u3.y)
        + b2f(u4.y) + b2f(u5.y) + b2f(u6.y) + b2f(u7.y);
    a2 += b2f(u0.z) + b2f(u1.z) + b2f(u2.z) + b2f(u3.z)
        + b2f(u4.z) + b2f(u5.z) + b2f(u6.z) + b2f(u7.z);
    a3 += b2f(u0.w) + b2f(u1.w) + b2f(u2.w) + b2f(u3.w)
        + b2f(u4.w) + b2f(u5.w) + b2f(u6.w) + b2f(u7.w);
  }
  for (; i + 4 <= deg; i += 4) {
    int s0 = csr[beg + i + 0], s1 = csr[beg + i + 1];
    int s2 = csr[beg + i + 2], s3 = csr[beg + i + 3];
    ushort4 u0 = hv[(size_t)s0 * 64], u1 = hv[(size_t)s1 * 64];
    ushort4 u2 = hv[(size_t)s2 * 64], u3 = hv[(size_t)s3 * 64];
    a0 += b2f(u0.x) + b2f(u1.x) + b2f(u2.x) + b2f(u3.x);
    a1 += b2f(u0.y) + b2f(u1.y) + b2f(u2.y) + b2f(u3.y);
    a2 += b2f(u0.z) + b2f(u1.z) + b2f(u2.z) + b2f(u3.z);
    a3 += b2f(u0.w) + b2f(u1.w) + b2f(u2.w) + b2f(u3.w);
  }
  for (; i < deg; ++i) {
    int s = csr[beg + i];
    ushort4 u = hv[(size_t)s * 64];
    a0 += b2f(u.x); a1 += b2f(u.y); a2 += b2f(u.z); a3 += b2f(u.w);
  }
  ushort4 o;
  o.x = f2b(a0); o.y = f2b(a1); o.z = f2b(a2); o.w = f2b(a3);
  *((ushort4*)out + (size_t)node * 64 + l) = o;
}

// ---------------- GEMM (proj only): C = relu(A @ W + bias) ----------------
__global__ __launch_bounds__(256) void k_gemm(const u16* __restrict__ A,
                                              const u16* __restrict__ BT,
                                              const float* __restrict__ bias,
                                              u16* __restrict__ C, int relu) {
  __shared__ __align__(16) u16 As[128 * LDSW];
  __shared__ __align__(16) u16 Bs[128 * LDSW];
  int tid = threadIdx.x;
  int bid = blockIdx.x;
  int tn = bid & 1, tm = bid >> 1;
  int w = tid >> 6, l = tid & 63;
  int wr = (w >> 1) * 64, wc = (w & 1) * 64;

  const u16* Ag = A + (size_t)tm * 128 * 256;
  const u16* Bg = BT + (size_t)tn * 128 * 256;

  f32x4 zz; zz[0] = 0.f; zz[1] = 0.f; zz[2] = 0.f; zz[3] = 0.f;
  f32x4 acc[4][4];
#pragma unroll
  for (int m = 0; m < 4; ++m)
#pragma unroll
    for (int n = 0; n < 4; ++n) acc[m][n] = zz;

  int r0 = w * 16 + (l >> 2);
  int r1 = r0 + 64;
  int kc = (l & 3) * 8;
  int w0 = r0 * LDSW + (l & 3) * 8;
  int w1 = r1 * LDSW + (l & 3) * 8;

  short8 pa0 = *(const short8*)(Ag + (size_t)r0 * 256 + kc);
  short8 pa1 = *(const short8*)(Ag + (size_t)r1 * 256 + kc);
  short8 pb0 = *(const short8*)(Bg + (size_t)r0 * 256 + kc);
  short8 pb1 = *(const short8*)(Bg + (size_t)r1 * 256 + kc);

  for (int kk = 0; kk < 8; ++kk) {
    *(short8*)&As[w0] = pa0;
    *(short8*)&As[w1] = pa1;
    *(short8*)&Bs[w0] = pb0;
    *(short8*)&Bs[w1] = pb1;
    if (kk < 7) {
      int k0 = (kk + 1) * 32 + kc;
      pa0 = *(const short8*)(Ag + (size_t)r0 * 256 + k0);
      pa1 = *(const short8*)(Ag + (size_t)r1 * 256 + k0);
      pb0 = *(const short8*)(Bg + (size_t)r0 * 256 + k0);
      pb1 = *(const short8*)(Bg + (size_t)r1 * 256 + k0);
    }
    __syncthreads();
    short8 af[4], bfr[4];
#pragma unroll
    for (int m = 0; m < 4; ++m) {
      int row = wr + m * 16 + (l & 15);
      af[m] = *(const short8*)&As[row * LDSW + (l >> 4) * 8];
    }
#pragma unroll
    for (int n = 0; n < 4; ++n) {
      int row = wc + n * 16 + (l & 15);
      bfr[n] = *(const short8*)&Bs[row * LDSW + (l >> 4) * 8];
    }
#pragma unroll
    for (int m = 0; m < 4; ++m)
#pragma unroll
      for (int n = 0; n < 4; ++n)
        acc[m][n] = __builtin_amdgcn_mfma_f32_16x16x32_bf16(af[m], bfr[n], acc[m][n], 0, 0, 0);
    __syncthreads();
  }

  int colb = tn * 128 + wc;
  int rowb = tm * 128 + wr + (l >> 4) * 4;
#pragma unroll
  for (int n = 0; n < 4; ++n) {
    int c = colb + n * 16 + (l & 15);
    float bz = bias[c];
#pragma unroll
    for (int m = 0; m < 4; ++m) {
      int r = rowb + m * 16;
#pragma unroll
      for (int i = 0; i < 4; ++i) {
        float v = acc[m][n][i] + bz;
        if (relu) v = fmaxf(v, 0.f);
        C[(size_t)(r + i) * 256 + c] = f2b(v);
      }
    }
  }
}

// ---------------- fused GIN MLP: C = relu(A@W1+b1)@W2+b2, stats fused ----------------
// block: 64 rows x 256 cols; 4 waves each 64r x 64c; C1 kept bf16 in LDS (chunk-major)
__global__ __launch_bounds__(256) void k_mlp(const u16* __restrict__ A,
                                             const u16* __restrict__ B1T,
                                             const u16* __restrict__ B2T,
                                             const float* __restrict__ b1,
                                             const float* __restrict__ b2,
                                             u16* __restrict__ C,
                                             float* __restrict__ csum,
                                             float* __restrict__ csq) {
  __shared__ __align__(16) u16 As[64 * LDSW];
  __shared__ __align__(16) u16 Bs[256 * LDSW];
  __shared__ __align__(16) u16 C1[8 * 64 * LDSW];  // [chunk][row][k&31]
  int tid = threadIdx.x;
  int tm = blockIdx.x;
  int w = tid >> 6, l = tid & 63;
  int wc = w * 64;

  const u16* Ag = A + (size_t)tm * 64 * 256;

  int sr = tid >> 2;            // 0..63
  int skc = (tid & 3) * 8;      // k offset in chunk
  int aw = sr * LDSW + skc;

  f32x4 zz; zz[0] = 0.f; zz[1] = 0.f; zz[2] = 0.f; zz[3] = 0.f;
  f32x4 acc[4][4];
#pragma unroll
  for (int m = 0; m < 4; ++m)
#pragma unroll
    for (int n = 0; n < 4; ++n) acc[m][n] = zz;

  // ---- phase 1: C1 = relu(A @ W1 + b1) ----
  short8 pa = *(const short8*)(Ag + (size_t)sr * 256 + skc);
  short8 pb[4];
#pragma unroll
  for (int j = 0; j < 4; ++j)
    pb[j] = *(const short8*)(B1T + (size_t)(sr + 64 * j) * 256 + skc);

  for (int kk = 0; kk < 8; ++kk) {
    *(short8*)&As[aw] = pa;
#pragma unroll
    for (int j = 0; j < 4; ++j)
      *(short8*)&Bs[(sr + 64 * j) * LDSW + skc] = pb[j];
    if (kk < 7) {
      int k0 = (kk + 1) * 32 + skc;
      pa = *(const short8*)(Ag + (size_t)sr * 256 + k0);
#pragma unroll
      for (int j = 0; j < 4; ++j)
        pb[j] = *(const short8*)(B1T + (size_t)(sr + 64 * j) * 256 + k0);
    }
    __syncthreads();
    short8 af[4], bfr[4];
#pragma unroll
    for (int m = 0; m < 4; ++m)
      af[m] = *(const short8*)&As[(m * 16 + (l & 15)) * LDSW + (l >> 4) * 8];
#pragma unroll
    for (int n = 0; n < 4; ++n)
      bfr[n] = *(const short8*)&Bs[(wc + n * 16 + (l & 15)) * LDSW + (l >> 4) * 8];
#pragma unroll
    for (int m = 0; m < 4; ++m)
#pragma unroll
      for (int n = 0; n < 4; ++n)
        acc[m][n] = __builtin_amdgcn_mfma_f32_16x16x32_bf16(af[m], bfr[n], acc[m][n], 0, 0, 0);
    __syncthreads();
  }

  // prefetch W2 chunk 0 (hide latency under epilogue 1)
  short8 qb[4];
#pragma unroll
  for (int j = 0; j < 4; ++j)
    qb[j] = *(const short8*)(B2T + (size_t)(sr + 64 * j) * 256 + skc);

  // epilogue 1 -> C1 (LDS, chunk-major), add b1, relu
  {
    int rbase = (l >> 4) * 4;
#pragma unroll
    for (int n = 0; n < 4; ++n) {
      int c = wc + n * 16 + (l & 15);
      float bz = b1[c];
      u16* c1p = &C1[(c >> 5) * (64 * LDSW) + (c & 31)];
#pragma unroll
      for (int m = 0; m < 4; ++m) {
#pragma unroll
        for (int i = 0; i < 4; ++i) {
          float v = fmaxf(acc[m][n][i] + bz, 0.f);
          c1p[(m * 16 + rbase + i) * LDSW] = f2b(v);
        }
        acc[m][n] = zz;  // re-zero for phase 2
      }
    }
  }

  // ---- phase 2: C = C1 @ W2 + b2 ----
  for (int kk = 0; kk < 8; ++kk) {
#pragma unroll
    for (int j = 0; j < 4; ++j)
      *(short8*)&Bs[(sr + 64 * j) * LDSW + skc] = qb[j];
    if (kk < 7) {
      int k0 = (kk + 1) * 32 + skc;
#pragma unroll
      for (int j = 0; j < 4; ++j)
        qb[j] = *(const short8*)(B2T + (size_t)(sr + 64 * j) * 256 + k0);
    }
    __syncthreads();  // C1 writes (kk=0) + Bs chunk visible
    short8 af[4], bfr[4];
#pragma unroll
    for (int m = 0; m < 4; ++m)
      af[m] = *(const short8*)&C1[kk * (64 * LDSW) + (m * 16 + (l & 15)) * LDSW + (l >> 4) * 8];
#pragma unroll
    for (int n = 0; n < 4; ++n)
      bfr[n] = *(const short8*)&Bs[(wc + n * 16 + (l & 15)) * LDSW + (l >> 4) * 8];
#pragma unroll
    for (int m = 0; m < 4; ++m)
#pragma unroll
      for (int n = 0; n < 4; ++n)
        acc[m][n] = __builtin_amdgcn_mfma_f32_16x16x32_bf16(af[m], bfr[n], acc[m][n], 0, 0, 0);
    __syncthreads();
  }

  // epilogue 2 -> global + fused stats
  int rowb = tm * 64 + (l >> 4) * 4;
#pragma unroll
  for (int n = 0; n < 4; ++n) {
    int c = wc + n * 16 + (l & 15);
    float bz = b2[c];
    float s = 0.f, q = 0.f;
#pragma unroll
    for (int m = 0; m < 4; ++m) {
      int r = rowb + m * 16;
#pragma unroll
      for (int i = 0; i < 4; ++i) {
        float v = acc[m][n][i] + bz;
        C[(size_t)(r + i) * 256 + c] = f2b(v);
        if ((r + i) < NN) { s += v; q += v * v; }
      }
    }
    s += __shfl_xor(s, 16); s += __shfl_xor(s, 32);
    q += __shfl_xor(q, 16); q += __shfl_xor(q, 32);
    if ((l >> 4) == 0) {
      atomicAdd(&csum[c], s);
      atomicAdd(&csq[c], q);
    }
  }
}

// ---------------- pooling (batch sorted) ----------------
__global__ void k_pool(const u16* __restrict__ h, const int* __restrict__ batch,
                       float* __restrict__ pooled, int* __restrict__ gcnt) {
  __shared__ int bg[128];
  int t = threadIdx.x;
  int r0 = blockIdx.x * 128;
  int rend = min(r0 + 128, NN);
  if (r0 >= NN) return;
  if (t < 128 && r0 + t < NN) bg[t] = batch[r0 + t];
  __syncthreads();
  float a = 0.f;
  int cur = bg[0];
  int cl = 0;
  for (int r = r0; r < rend; ++r) {
    int g = bg[r - r0];
    if (g != cur) {
      atomicAdd(&pooled[(size_t)cur * 256 + t], a);
      if (t == 0) atomicAdd(&gcnt[cur], cl);
      a = 0.f; cl = 0; cur = g;
    }
    a += b2f(h[(size_t)r * 256 + t]);
    cl++;
  }
  atomicAdd(&pooled[(size_t)cur * 256 + t], a);
  if (t == 0) atomicAdd(&gcnt[cur], cl);
}

// ---------------- head: embed + logits (fp32 out) ----------------
__global__ void k_head(const float* __restrict__ pooled, const int* __restrict__ gcnt,
                       const float* __restrict__ predW, const float* __restrict__ predb,
                       float* __restrict__ out) {
  __shared__ float pm[256];
  int g = blockIdx.x, t = threadIdx.x;
  float c = fmaxf((float)gcnt[g], 1.0f);
  float v = pooled[(size_t)g * 256 + t] / c;
  pm[t] = v;
  out[(size_t)g * 256 + t] = v;
  __syncthreads();
  if (t < NOTESD) {
    float acc = predb[t];
    for (int k = 0; k < 256; ++k)
      acc += pm[k] * predW[k * NOTESD + t];
    out[(size_t)GG * 256 + (size_t)g * NOTESD + t] = acc;
  }
}

extern "C" void kernel_launch(void* const* d_in, const int* in_sizes, int n_in,
                              void* d_out, int out_size, void* d_ws, size_t ws_size,
                              hipStream_t stream) {
  const float* x     = (const float*)d_in[0];
  const int*   ei    = (const int*)d_in[1];
  const int*   batch = (const int*)d_in[2];
  const float* fng   = (const float*)d_in[3];
  const float* fnb   = (const float*)d_in[4];
  const float* projW = (const float*)d_in[5];
  const float* projb = (const float*)d_in[6];
  const float* W1    = (const float*)d_in[7];
  const float* b1    = (const float*)d_in[8];
  const float* W2    = (const float*)d_in[9];
  const float* b2    = (const float*)d_in[10];
  const float* bng   = (const float*)d_in[11];
  const float* bnb   = (const float*)d_in[12];
  const float* predW = (const float*)d_in[13];
  const float* predb = (const float*)d_in[14];
  float* out = (float*)d_out;

  char* ws = (char*)d_ws;
  size_t off = 0;
  auto alloc = [&](size_t b) { size_t o = off; off += (b + 255) & ~(size_t)255; return o; };
  u16* h    = (u16*)(ws + alloc((size_t)MPAD * 256 * 2));
  u16* bufA = (u16*)(ws + alloc((size_t)MPAD * 256 * 2));
  u16* bufB = (u16*)(ws + alloc((size_t)MPAD * 256 * 2));
  u16* wt   = (u16*)(ws + alloc((size_t)9 * 65536 * 2));
  int* cnt    = (int*)(ws + alloc((size_t)NN * 4));
  int* indptr = (int*)(ws + alloc((size_t)NN * 4));
  int* cursor = (int*)(ws + alloc((size_t)NN * 4));
  int* csum   = (int*)(ws + alloc(512));
  int* coff   = (int*)(ws + alloc(512));
  int* csr    = (int*)(ws + alloc((size_t)EE * 4));
  size_t statbytes = (size_t)(2560 + GG * 256) * 4 + GG * 4;
  float* statz = (float*)(ws + alloc(statbytes));
  float* xsum = statz;
  float* xsq  = statz + 256;
  float* pooled = statz + 2560;
  int* gcnt = (int*)(statz + 2560 + GG * 256);

  const int* srcI = ei;
  const int* dstI = ei + EE;

  // CSR build
  hipMemsetAsync(cnt, 0, (size_t)NN * 4, stream);
  k_hist<<<(EE + 255) / 256, 256, 0, stream>>>(dstI, cnt);
  k_scan1<<<NCHUNK, 512, 0, stream>>>(cnt, indptr, csum);
  k_scan2<<<1, 128, 0, stream>>>(csum, coff);
  k_scan3<<<NCHUNK, 512, 0, stream>>>(coff, indptr, cursor);
  k_fill<<<(EE + 255) / 256, 256, 0, stream>>>(srcI, dstI, cursor, csr);

  // all weight transposes in one launch
  k_transpose_all<<<576, 256, 0, stream>>>(projW, W1, W2, wt);

  // zero accumulators + bufA pad rows (once)
  hipMemsetAsync(statz, 0, statbytes, stream);
  hipMemsetAsync(bufA + (size_t)NN * 256, 0, (size_t)(MPAD - NN) * 256 * 2, stream);

  // feature BN -> bufA
  k_colstats_f32<<<512, 256, 0, stream>>>(x, xsum, xsq);
  k_bnx<<<512, 256, 0, stream>>>(x, xsum, xsq, fng, fnb, bufA);

  // projection: h = relu(xn @ projW + projb)
  k_gemm<<<TM_TILES * 2, 256, 0, stream>>>(bufA, wt, projb, h, 1);

  for (int l = 0; l < 4; ++l) {
    float* lsum = statz + 512 + l * 512;
    float* lsq  = lsum + 256;
    k_agg<<<(NN + 3) / 4, 256, 0, stream>>>(h, indptr, cnt, csr, bufA);
    k_mlp<<<MPAD / 64, 256, 0, stream>>>(bufA, wt + (size_t)(1 + l) * 65536,
                                         wt + (size_t)(5 + l) * 65536,
                                         b1 + (size_t)l * 256, b2 + (size_t)l * 256,
                                         bufB, lsum, lsq);
    k_bnres<<<512, 256, 0, stream>>>(bufB, lsum, lsq, bng + (size_t)l * 256,
                                     bnb + (size_t)l * 256, h);
  }

  // readout
  k_pool<<<(NN + 127) / 128, 256, 0, stream>>>(h, batch, pooled, gcnt);
  k_head<<<GG, 256, 0, stream>>>(pooled, gcnt, predW, predb, out);
}